// Round 1
// baseline (2487.108 us; speedup 1.0000x reference)
//
#include <hip/hip_runtime.h>
#include <hip/hip_bf16.h>
#include <math.h>

#define N_NODES 10000
#define N_EDGES 160000
#define D 512
#define DIN 20
#define B 64
#define KC 10
#define DH 256
#define NROW (B*KC)   // 640
#define BN_EPS 1e-5f

// ---------------- degree ----------------
__global__ void deg_kernel(const int* __restrict__ dst, float* __restrict__ deg, int E){
  int i = blockIdx.x*blockDim.x + threadIdx.x;
  if (i < E) atomicAdd(&deg[dst[i]], 1.0f);
}

// ---------------- h = x @ W_init + b_init ----------------
__global__ void init_mm_kernel(const float* __restrict__ x, const float* __restrict__ W,
                               const float* __restrict__ b, float* __restrict__ h){
  __shared__ float xs[DIN];
  int row = blockIdx.x;
  int t = threadIdx.x;
  if (t < DIN) xs[t] = x[row*DIN + t];
  __syncthreads();
  #pragma unroll
  for (int half = 0; half < 2; ++half){
    int col = t + half*256;
    float acc = b[col];
    #pragma unroll
    for (int k = 0; k < DIN; ++k) acc += xs[k]*W[k*D+col];
    h[(size_t)row*D + col] = acc;
  }
}

// ---------------- edge scatter: agg[dst] += h[src] ----------------
__global__ void scatter_kernel(const float* __restrict__ h, const int* __restrict__ src,
                               const int* __restrict__ dst, float* __restrict__ agg, int E){
  int wave = threadIdx.x >> 6;
  int lane = threadIdx.x & 63;
  int e = blockIdx.x*4 + wave;
  if (e >= E) return;
  const float4* hs = (const float4*)(h + (size_t)src[e]*D);
  float* ag = agg + (size_t)dst[e]*D;
  #pragma unroll
  for (int j = 0; j < 2; ++j){
    int idx = lane + 64*j;
    float4 v = hs[idx];
    atomicAdd(&ag[idx*4+0], v.x);
    atomicAdd(&ag[idx*4+1], v.y);
    atomicAdd(&ag[idx*4+2], v.z);
    atomicAdd(&ag[idx*4+3], v.w);
  }
}

// ---------------- h2 = h + agg/max(deg,1), accumulate BN column stats ----------------
#define CS_ROWS 8
__global__ void combine_stats_kernel(const float* __restrict__ h, float* __restrict__ agg,
                                     const float* __restrict__ deg,
                                     float* __restrict__ csum, float* __restrict__ csq){
  int t = threadIdx.x;
  int r0 = blockIdx.x*CS_ROWS;
  float s0=0.f,s1=0.f,q0=0.f,q1=0.f;
  for (int rr=0; rr<CS_ROWS; ++rr){
    int r = r0+rr;
    float inv = 1.0f/fmaxf(deg[r],1.0f);
    size_t base = (size_t)r*D;
    float v0 = h[base+t]     + agg[base+t]*inv;
    float v1 = h[base+t+256] + agg[base+t+256]*inv;
    agg[base+t]=v0; agg[base+t+256]=v1;
    s0+=v0; q0+=v0*v0; s1+=v1; q1+=v1*v1;
  }
  atomicAdd(&csum[t],     s0);
  atomicAdd(&csum[t+256], s1);
  atomicAdd(&csq[t],      q0);
  atomicAdd(&csq[t+256],  q1);
}

// ---------------- h = relu(BN(h2)) ----------------
__global__ void bn_relu_kernel(const float* __restrict__ in, float* __restrict__ out,
                               const float* __restrict__ csum, const float* __restrict__ csq,
                               const float* __restrict__ gamma, const float* __restrict__ beta){
  int i = blockIdx.x*blockDim.x + threadIdx.x; // float4 index
  const int total = N_NODES*(D/4);
  if (i >= total) return;
  int c = (i & (D/4 - 1))*4;
  float4 v = ((const float4*)in)[i];
  const float invN = 1.0f/(float)N_NODES;
  float4 o;
  float* vp = &v.x; float* op = &o.x;
  #pragma unroll
  for (int j=0;j<4;++j){
    float mu = csum[c+j]*invN;
    float var = csq[c+j]*invN - mu*mu;
    float rs = rsqrtf(var + BN_EPS);
    op[j] = fmaxf((vp[j]-mu)*rs*gamma[c+j] + beta[c+j], 0.0f);
  }
  ((float4*)out)[i] = o;
}

// ---------------- per-graph mean readout (sums + counts) ----------------
#define RO_ROWS 16
__global__ void readout_kernel(const float* __restrict__ h, const int* __restrict__ n2g,
                               float* __restrict__ qemb, float* __restrict__ gcnt){
  int t = threadIdx.x;
  int r0 = blockIdx.x*RO_ROWS;
  for (int rr=0; rr<RO_ROWS; ++rr){
    int r = r0+rr;
    int g = n2g[r];
    size_t base = (size_t)r*D;
    atomicAdd(&qemb[(size_t)g*D + t],       h[base+t]);
    atomicAdd(&qemb[(size_t)g*D + t + 256], h[base+t+256]);
    if (t==0) atomicAdd(&gcnt[g], 1.0f);
  }
}

// ---------------- FC1: [640,1536]@[1536,256] + bias, accumulate stats ----------------
#define FC_ROWS 8
__global__ void fc1_kernel(const float* __restrict__ qemb, const float* __restrict__ gcnt,
                           const float* __restrict__ pg, const float* __restrict__ neigh,
                           const float* __restrict__ W, const float* __restrict__ bias,
                           float* __restrict__ out, float* __restrict__ s, float* __restrict__ q){
  __shared__ float brow[FC_ROWS][3*D];
  int t = threadIdx.x;
  int r0 = blockIdx.x*FC_ROWS;
  for (int rr=0; rr<FC_ROWS; ++rr){
    int r = r0+rr;
    int g = r/KC, k = r - g*KC;
    float invc = 1.0f/fmaxf(gcnt[g],1.0f);
    for (int j = t; j < 3*D; j += 256){
      float v;
      if (j < D)        v = qemb[(size_t)g*D+j]*invc;
      else if (j < 2*D) v = pg[(size_t)g*D + (j-D)];
      else              v = neigh[((size_t)g*KC + k)*D + (j-2*D)];
      brow[rr][j] = v;
    }
  }
  __syncthreads();
  int col = t;
  float acc[FC_ROWS];
  #pragma unroll
  for (int rr=0;rr<FC_ROWS;++rr) acc[rr] = bias[col];
  for (int kk=0; kk<3*D; ++kk){
    float w = W[kk*DH + col];
    #pragma unroll
    for (int rr=0;rr<FC_ROWS;++rr) acc[rr] += brow[rr][kk]*w;
  }
  float ls=0.f,lq=0.f;
  #pragma unroll
  for (int rr=0;rr<FC_ROWS;++rr){
    out[(size_t)(r0+rr)*DH + col] = acc[rr];
    ls += acc[rr]; lq += acc[rr]*acc[rr];
  }
  atomicAdd(&s[col], ls); atomicAdd(&q[col], lq);
}

// ---------------- FC mid: BN(prev)+relu staged, @[256,256] + bias, stats ----------------
__global__ void fc_mid_kernel(const float* __restrict__ in, const float* __restrict__ ps,
                              const float* __restrict__ pq, const float* __restrict__ gamma,
                              const float* __restrict__ beta,
                              const float* __restrict__ W, const float* __restrict__ bias,
                              float* __restrict__ out, float* __restrict__ s, float* __restrict__ q){
  __shared__ float row[FC_ROWS][DH];
  int t = threadIdx.x;
  int r0 = blockIdx.x*FC_ROWS;
  const float invM = 1.0f/(float)NROW;
  float mu = ps[t]*invM;
  float var = pq[t]*invM - mu*mu;
  float rs = rsqrtf(var+BN_EPS);
  float ga = gamma[t], be = beta[t];
  for (int rr=0; rr<FC_ROWS; ++rr){
    float v = in[(size_t)(r0+rr)*DH + t];
    row[rr][t] = fmaxf((v-mu)*rs*ga + be, 0.0f);
  }
  __syncthreads();
  float acc[FC_ROWS];
  #pragma unroll
  for (int rr=0;rr<FC_ROWS;++rr) acc[rr]=bias[t];
  for (int kk=0; kk<DH; ++kk){
    float w = W[kk*DH + t];
    #pragma unroll
    for (int rr=0;rr<FC_ROWS;++rr) acc[rr] += row[rr][kk]*w;
  }
  float ls=0.f,lq=0.f;
  #pragma unroll
  for (int rr=0;rr<FC_ROWS;++rr){
    out[(size_t)(r0+rr)*DH+t]=acc[rr];
    ls+=acc[rr]; lq+=acc[rr]*acc[rr];
  }
  atomicAdd(&s[t],ls); atomicAdd(&q[t],lq);
}

// ---------------- final: BN3+relu, dot W_fc4, sigmoid ----------------
__global__ void final_kernel(const float* __restrict__ G3, const float* __restrict__ ps,
                             const float* __restrict__ pq, const float* __restrict__ gamma,
                             const float* __restrict__ beta,
                             const float* __restrict__ w4, const float* __restrict__ b4,
                             float* __restrict__ out){
  int wave = threadIdx.x>>6, lane = threadIdx.x&63;
  int r = blockIdx.x*4 + wave;
  if (r >= NROW) return;
  const float invM = 1.0f/(float)NROW;
  float sum = 0.f;
  #pragma unroll
  for (int j=0;j<4;++j){
    int c = lane + 64*j;
    float mu = ps[c]*invM;
    float var = pq[c]*invM - mu*mu;
    float rs = rsqrtf(var+BN_EPS);
    float v = G3[(size_t)r*DH + c];
    v = fmaxf((v-mu)*rs*gamma[c]+beta[c], 0.0f);
    sum += v*w4[c];
  }
  #pragma unroll
  for (int off=32; off>0; off>>=1) sum += __shfl_down(sum, off, 64);
  if (lane==0){
    float z = sum + b4[0];
    out[r] = 1.0f/(1.0f + expf(-z));
  }
}

extern "C" void kernel_launch(void* const* d_in, const int* in_sizes, int n_in,
                              void* d_out, int out_size, void* d_ws, size_t ws_size,
                              hipStream_t stream) {
  const float* x        = (const float*)d_in[0];
  const float* pg_emb   = (const float*)d_in[1];
  const float* neigh    = (const float*)d_in[2];
  const float* W_init   = (const float*)d_in[3];
  const float* b_init   = (const float*)d_in[4];
  const float* g1       = (const float*)d_in[5];
  const float* be1      = (const float*)d_in[6];
  const float* g2       = (const float*)d_in[7];
  const float* be2      = (const float*)d_in[8];
  const float* W_fc     = (const float*)d_in[9];
  const float* b_fc     = (const float*)d_in[10];
  const float* W_fc2    = (const float*)d_in[11];
  const float* b_fc2    = (const float*)d_in[12];
  const float* W_fc3    = (const float*)d_in[13];
  const float* b_fc3    = (const float*)d_in[14];
  const float* W_fc4    = (const float*)d_in[15];
  const float* b_fc4    = (const float*)d_in[16];
  const float* gb       = (const float*)d_in[17];
  const float* bb       = (const float*)d_in[18];
  const float* gb2      = (const float*)d_in[19];
  const float* bb2      = (const float*)d_in[20];
  const float* gb3      = (const float*)d_in[21];
  const float* bb3      = (const float*)d_in[22];
  const int*   esrc     = (const int*)d_in[23];
  const int*   edst     = (const int*)d_in[24];
  const int*   n2g      = (const int*)d_in[25];
  float* out = (float*)d_out;

  float* ws = (float*)d_ws;
  size_t off = 0;
  float* h    = ws + off; off += (size_t)N_NODES*D;   // 5,120,000
  float* agg  = ws + off; off += (size_t)N_NODES*D;   // 5,120,000
  float* deg  = ws + off; off += 10240;
  float* csum = ws + off; off += 512;
  float* csq  = ws + off; off += 512;
  float* qemb = ws + off; off += (size_t)B*D;
  float* gcnt = ws + off; off += 64;
  float* G1   = ws + off; off += (size_t)NROW*DH;
  float* G2   = ws + off; off += (size_t)NROW*DH;
  float* G3   = ws + off; off += (size_t)NROW*DH;
  float* s1   = ws + off; off += 256;
  float* q1   = ws + off; off += 256;
  float* s2   = ws + off; off += 256;
  float* q2   = ws + off; off += 256;
  float* s3   = ws + off; off += 256;
  float* q3   = ws + off; off += 256;

  // degree (same for both layers)
  hipMemsetAsync(deg, 0, (size_t)N_NODES*sizeof(float), stream);
  deg_kernel<<<(N_EDGES+255)/256, 256, 0, stream>>>(edst, deg, N_EDGES);

  // initial projection
  init_mm_kernel<<<N_NODES, 256, 0, stream>>>(x, W_init, b_init, h);

  // two GIN(mean) + BN + ReLU layers
  const float* gs[2] = {g1, g2};
  const float* bs[2] = {be1, be2};
  for (int layer = 0; layer < 2; ++layer){
    hipMemsetAsync(agg, 0, (size_t)N_NODES*D*sizeof(float), stream);
    scatter_kernel<<<(N_EDGES+3)/4, 256, 0, stream>>>(h, esrc, edst, agg, N_EDGES);
    hipMemsetAsync(csum, 0, 1024*sizeof(float), stream); // csum+csq contiguous
    combine_stats_kernel<<<N_NODES/CS_ROWS, 256, 0, stream>>>(h, agg, deg, csum, csq);
    bn_relu_kernel<<<(N_NODES*(D/4)+255)/256, 256, 0, stream>>>(agg, h, csum, csq, gs[layer], bs[layer]);
  }

  // per-graph mean readout
  hipMemsetAsync(qemb, 0, ((size_t)B*D + 64)*sizeof(float), stream); // qemb+gcnt contiguous
  readout_kernel<<<N_NODES/RO_ROWS, 256, 0, stream>>>(h, n2g, qemb, gcnt);

  // MLP head
  hipMemsetAsync(s1, 0, 6*256*sizeof(float), stream); // s1..q3 contiguous
  fc1_kernel<<<NROW/FC_ROWS, 256, 0, stream>>>(qemb, gcnt, pg_emb, neigh, W_fc, b_fc, G1, s1, q1);
  fc_mid_kernel<<<NROW/FC_ROWS, 256, 0, stream>>>(G1, s1, q1, gb,  bb,  W_fc2, b_fc2, G2, s2, q2);
  fc_mid_kernel<<<NROW/FC_ROWS, 256, 0, stream>>>(G2, s2, q2, gb2, bb2, W_fc3, b_fc3, G3, s3, q3);
  final_kernel<<<(NROW+3)/4, 256, 0, stream>>>(G3, s3, q3, gb3, bb3, W_fc4, b_fc4, out);
}

// Round 2
// 865.467 us; speedup vs baseline: 2.8737x; 2.8737x over previous
//
#include <hip/hip_runtime.h>
#include <hip/hip_bf16.h>
#include <math.h>

#define N_NODES 10000
#define N_EDGES 160000
#define D 512
#define DIN 20
#define B 64
#define KC 10
#define DH 256
#define NROW (B*KC)   // 640
#define BN_EPS 1e-5f

// ---------------- degree histogram (int) ----------------
__global__ void deg_kernel(const int* __restrict__ dst, int* __restrict__ degi, int E){
  int i = blockIdx.x*blockDim.x + threadIdx.x;
  if (i < E) atomicAdd(&degi[dst[i]], 1);
}

// ---------------- single-block exclusive scan over 10000 degrees ----------------
__global__ void scan_kernel(const int* __restrict__ degi, int* __restrict__ rowstart,
                            int* __restrict__ cursor){
  __shared__ int part[256];
  int t = threadIdx.x;
  const int PER = (N_NODES + 255)/256; // 40
  int base = t*PER;
  int s = 0;
  for (int i = 0; i < PER; ++i){
    int idx = base+i;
    if (idx < N_NODES) s += degi[idx];
  }
  part[t] = s;
  __syncthreads();
  // Hillis-Steele inclusive scan of 256 partials
  for (int off = 1; off < 256; off <<= 1){
    int v = (t >= off) ? part[t-off] : 0;
    __syncthreads();
    part[t] += v;
    __syncthreads();
  }
  int run = (t > 0) ? part[t-1] : 0;
  for (int i = 0; i < PER; ++i){
    int idx = base+i;
    if (idx < N_NODES){
      rowstart[idx] = run; cursor[idx] = run; run += degi[idx];
    }
  }
  if (t == 255) rowstart[N_NODES] = run;
}

// ---------------- CSR fill: csr[pos] = src, bucketed by dst ----------------
__global__ void fill_kernel(const int* __restrict__ src, const int* __restrict__ dst,
                            int* __restrict__ cursor, int* __restrict__ csr, int E){
  int i = blockIdx.x*blockDim.x + threadIdx.x;
  if (i < E){
    int p = atomicAdd(&cursor[dst[i]], 1);
    csr[p] = src[i];
  }
}

// ---------------- h = x @ W_init + b_init ----------------
__global__ void init_mm_kernel(const float* __restrict__ x, const float* __restrict__ W,
                               const float* __restrict__ b, float* __restrict__ h){
  __shared__ float xs[DIN];
  int row = blockIdx.x;
  int t = threadIdx.x;
  if (t < DIN) xs[t] = x[row*DIN + t];
  __syncthreads();
  #pragma unroll
  for (int half = 0; half < 2; ++half){
    int col = t + half*256;
    float acc = b[col];
    #pragma unroll
    for (int k = 0; k < DIN; ++k) acc += xs[k]*W[k*D+col];
    h[(size_t)row*D + col] = acc;
  }
}

// ---------------- GIN gather: h2 = h + mean_{src in N(dst)} h[src]; BN stats ----------------
#define GN 4
__global__ void gin_gather_kernel(const float* __restrict__ h,
                                  const int* __restrict__ rowstart,
                                  const int* __restrict__ csr,
                                  float* __restrict__ h2,
                                  float* __restrict__ csum, float* __restrict__ csq){
  __shared__ int sidx[128];
  int t = threadIdx.x;             // 0..127, owns cols 4t..4t+3
  int n0 = blockIdx.x*GN;
  float s0=0.f,s1=0.f,s2=0.f,s3=0.f,q0=0.f,q1=0.f,q2=0.f,q3=0.f;
  for (int nn = 0; nn < GN; ++nn){
    int node = n0+nn;
    int start = rowstart[node], end = rowstart[node+1];
    float4 a = make_float4(0.f,0.f,0.f,0.f);
    float4 b = make_float4(0.f,0.f,0.f,0.f);
    for (int base = start; base < end; base += 128){
      int cnt = end - base; if (cnt > 128) cnt = 128;
      __syncthreads();
      if (t < cnt) sidx[t] = csr[base+t];
      __syncthreads();
      int i = 0;
      for (; i+1 < cnt; i += 2){
        float4 va = ((const float4*)(h + (size_t)sidx[i  ]*D))[t];
        float4 vb = ((const float4*)(h + (size_t)sidx[i+1]*D))[t];
        a.x+=va.x; a.y+=va.y; a.z+=va.z; a.w+=va.w;
        b.x+=vb.x; b.y+=vb.y; b.z+=vb.z; b.w+=vb.w;
      }
      if (i < cnt){
        float4 va = ((const float4*)(h + (size_t)sidx[i]*D))[t];
        a.x+=va.x; a.y+=va.y; a.z+=va.z; a.w+=va.w;
      }
    }
    float inv = 1.0f/fmaxf((float)(end-start), 1.0f);
    float4 hv = ((const float4*)(h + (size_t)node*D))[t];
    float4 o;
    o.x = hv.x + (a.x+b.x)*inv;
    o.y = hv.y + (a.y+b.y)*inv;
    o.z = hv.z + (a.z+b.z)*inv;
    o.w = hv.w + (a.w+b.w)*inv;
    ((float4*)(h2 + (size_t)node*D))[t] = o;
    s0+=o.x; q0+=o.x*o.x; s1+=o.y; q1+=o.y*o.y;
    s2+=o.z; q2+=o.z*o.z; s3+=o.w; q3+=o.w*o.w;
  }
  int c = 4*t;
  atomicAdd(&csum[c+0], s0); atomicAdd(&csum[c+1], s1);
  atomicAdd(&csum[c+2], s2); atomicAdd(&csum[c+3], s3);
  atomicAdd(&csq[c+0],  q0); atomicAdd(&csq[c+1],  q1);
  atomicAdd(&csq[c+2],  q2); atomicAdd(&csq[c+3],  q3);
}

// ---------------- h = relu(BN(h2)) ----------------
__global__ void bn_relu_kernel(const float* __restrict__ in, float* __restrict__ out,
                               const float* __restrict__ csum, const float* __restrict__ csq,
                               const float* __restrict__ gamma, const float* __restrict__ beta){
  int i = blockIdx.x*blockDim.x + threadIdx.x; // float4 index
  const int total = N_NODES*(D/4);
  if (i >= total) return;
  int c = (i & (D/4 - 1))*4;
  float4 v = ((const float4*)in)[i];
  const float invN = 1.0f/(float)N_NODES;
  float4 o;
  float* vp = &v.x; float* op = &o.x;
  #pragma unroll
  for (int j=0;j<4;++j){
    float mu = csum[c+j]*invN;
    float var = csq[c+j]*invN - mu*mu;
    float rs = rsqrtf(var + BN_EPS);
    op[j] = fmaxf((vp[j]-mu)*rs*gamma[c+j] + beta[c+j], 0.0f);
  }
  ((float4*)out)[i] = o;
}

// ---------------- per-graph mean readout (sums + counts) ----------------
#define RO_ROWS 16
__global__ void readout_kernel(const float* __restrict__ h, const int* __restrict__ n2g,
                               float* __restrict__ qemb, float* __restrict__ gcnt){
  int t = threadIdx.x;
  int r0 = blockIdx.x*RO_ROWS;
  for (int rr=0; rr<RO_ROWS; ++rr){
    int r = r0+rr;
    int g = n2g[r];
    size_t base = (size_t)r*D;
    atomicAdd(&qemb[(size_t)g*D + t],       h[base+t]);
    atomicAdd(&qemb[(size_t)g*D + t + 256], h[base+t+256]);
    if (t==0) atomicAdd(&gcnt[g], 1.0f);
  }
}

// ---------------- FC1: [640,1536]@[1536,256] + bias, accumulate stats ----------------
#define FC_ROWS 8
__global__ void fc1_kernel(const float* __restrict__ qemb, const float* __restrict__ gcnt,
                           const float* __restrict__ pg, const float* __restrict__ neigh,
                           const float* __restrict__ W, const float* __restrict__ bias,
                           float* __restrict__ out, float* __restrict__ s, float* __restrict__ q){
  __shared__ float brow[FC_ROWS][3*D];
  int t = threadIdx.x;
  int r0 = blockIdx.x*FC_ROWS;
  for (int rr=0; rr<FC_ROWS; ++rr){
    int r = r0+rr;
    int g = r/KC, k = r - g*KC;
    float invc = 1.0f/fmaxf(gcnt[g],1.0f);
    for (int j = t; j < 3*D; j += 256){
      float v;
      if (j < D)        v = qemb[(size_t)g*D+j]*invc;
      else if (j < 2*D) v = pg[(size_t)g*D + (j-D)];
      else              v = neigh[((size_t)g*KC + k)*D + (j-2*D)];
      brow[rr][j] = v;
    }
  }
  __syncthreads();
  int col = t;
  float acc[FC_ROWS];
  #pragma unroll
  for (int rr=0;rr<FC_ROWS;++rr) acc[rr] = bias[col];
  for (int kk=0; kk<3*D; ++kk){
    float w = W[kk*DH + col];
    #pragma unroll
    for (int rr=0;rr<FC_ROWS;++rr) acc[rr] += brow[rr][kk]*w;
  }
  float ls=0.f,lq=0.f;
  #pragma unroll
  for (int rr=0;rr<FC_ROWS;++rr){
    out[(size_t)(r0+rr)*DH + col] = acc[rr];
    ls += acc[rr]; lq += acc[rr]*acc[rr];
  }
  atomicAdd(&s[col], ls); atomicAdd(&q[col], lq);
}

// ---------------- FC mid: BN(prev)+relu staged, @[256,256] + bias, stats ----------------
__global__ void fc_mid_kernel(const float* __restrict__ in, const float* __restrict__ ps,
                              const float* __restrict__ pq, const float* __restrict__ gamma,
                              const float* __restrict__ beta,
                              const float* __restrict__ W, const float* __restrict__ bias,
                              float* __restrict__ out, float* __restrict__ s, float* __restrict__ q){
  __shared__ float row[FC_ROWS][DH];
  int t = threadIdx.x;
  int r0 = blockIdx.x*FC_ROWS;
  const float invM = 1.0f/(float)NROW;
  float mu = ps[t]*invM;
  float var = pq[t]*invM - mu*mu;
  float rs = rsqrtf(var+BN_EPS);
  float ga = gamma[t], be = beta[t];
  for (int rr=0; rr<FC_ROWS; ++rr){
    float v = in[(size_t)(r0+rr)*DH + t];
    row[rr][t] = fmaxf((v-mu)*rs*ga + be, 0.0f);
  }
  __syncthreads();
  float acc[FC_ROWS];
  #pragma unroll
  for (int rr=0;rr<FC_ROWS;++rr) acc[rr]=bias[t];
  for (int kk=0; kk<DH; ++kk){
    float w = W[kk*DH + t];
    #pragma unroll
    for (int rr=0;rr<FC_ROWS;++rr) acc[rr] += row[rr][kk]*w;
  }
  float ls=0.f,lq=0.f;
  #pragma unroll
  for (int rr=0;rr<FC_ROWS;++rr){
    out[(size_t)(r0+rr)*DH+t]=acc[rr];
    ls+=acc[rr]; lq+=acc[rr]*acc[rr];
  }
  atomicAdd(&s[t],ls); atomicAdd(&q[t],lq);
}

// ---------------- final: BN3+relu, dot W_fc4, sigmoid ----------------
__global__ void final_kernel(const float* __restrict__ G3, const float* __restrict__ ps,
                             const float* __restrict__ pq, const float* __restrict__ gamma,
                             const float* __restrict__ beta,
                             const float* __restrict__ w4, const float* __restrict__ b4,
                             float* __restrict__ out){
  int wave = threadIdx.x>>6, lane = threadIdx.x&63;
  int r = blockIdx.x*4 + wave;
  if (r >= NROW) return;
  const float invM = 1.0f/(float)NROW;
  float sum = 0.f;
  #pragma unroll
  for (int j=0;j<4;++j){
    int c = lane + 64*j;
    float mu = ps[c]*invM;
    float var = pq[c]*invM - mu*mu;
    float rs = rsqrtf(var+BN_EPS);
    float v = G3[(size_t)r*DH + c];
    v = fmaxf((v-mu)*rs*gamma[c]+beta[c], 0.0f);
    sum += v*w4[c];
  }
  #pragma unroll
  for (int off=32; off>0; off>>=1) sum += __shfl_down(sum, off, 64);
  if (lane==0){
    float z = sum + b4[0];
    out[r] = 1.0f/(1.0f + expf(-z));
  }
}

extern "C" void kernel_launch(void* const* d_in, const int* in_sizes, int n_in,
                              void* d_out, int out_size, void* d_ws, size_t ws_size,
                              hipStream_t stream) {
  const float* x        = (const float*)d_in[0];
  const float* pg_emb   = (const float*)d_in[1];
  const float* neigh    = (const float*)d_in[2];
  const float* W_init   = (const float*)d_in[3];
  const float* b_init   = (const float*)d_in[4];
  const float* g1       = (const float*)d_in[5];
  const float* be1      = (const float*)d_in[6];
  const float* g2       = (const float*)d_in[7];
  const float* be2      = (const float*)d_in[8];
  const float* W_fc     = (const float*)d_in[9];
  const float* b_fc     = (const float*)d_in[10];
  const float* W_fc2    = (const float*)d_in[11];
  const float* b_fc2    = (const float*)d_in[12];
  const float* W_fc3    = (const float*)d_in[13];
  const float* b_fc3    = (const float*)d_in[14];
  const float* W_fc4    = (const float*)d_in[15];
  const float* b_fc4    = (const float*)d_in[16];
  const float* gb       = (const float*)d_in[17];
  const float* bb       = (const float*)d_in[18];
  const float* gb2      = (const float*)d_in[19];
  const float* bb2      = (const float*)d_in[20];
  const float* gb3      = (const float*)d_in[21];
  const float* bb3      = (const float*)d_in[22];
  const int*   esrc     = (const int*)d_in[23];
  const int*   edst     = (const int*)d_in[24];
  const int*   n2g      = (const int*)d_in[25];
  float* out = (float*)d_out;

  float* ws = (float*)d_ws;
  size_t off = 0;
  float* h    = ws + off; off += (size_t)N_NODES*D;   // 5,120,000
  float* h2   = ws + off; off += (size_t)N_NODES*D;   // 5,120,000
  float* csum = ws + off; off += 512;
  float* csq  = ws + off; off += 512;
  float* qemb = ws + off; off += (size_t)B*D;
  float* gcnt = ws + off; off += 64;
  float* G1   = ws + off; off += (size_t)NROW*DH;
  float* G2   = ws + off; off += (size_t)NROW*DH;
  float* G3   = ws + off; off += (size_t)NROW*DH;
  float* s1   = ws + off; off += 256;
  float* q1   = ws + off; off += 256;
  float* s2   = ws + off; off += 256;
  float* q2   = ws + off; off += 256;
  float* s3   = ws + off; off += 256;
  float* q3   = ws + off; off += 256;
  int* degi     = (int*)(ws + off); off += N_NODES;
  int* rowstart = (int*)(ws + off); off += N_NODES + 1;
  int* cursor   = (int*)(ws + off); off += N_NODES;
  int* csr      = (int*)(ws + off); off += N_EDGES;

  // ---- build CSR (graph fixed per call) ----
  hipMemsetAsync(degi, 0, (size_t)N_NODES*sizeof(int), stream);
  deg_kernel<<<(N_EDGES+255)/256, 256, 0, stream>>>(edst, degi, N_EDGES);
  scan_kernel<<<1, 256, 0, stream>>>(degi, rowstart, cursor);
  fill_kernel<<<(N_EDGES+255)/256, 256, 0, stream>>>(esrc, edst, cursor, csr, N_EDGES);

  // ---- initial projection ----
  init_mm_kernel<<<N_NODES, 256, 0, stream>>>(x, W_init, b_init, h);

  // ---- two GIN(mean) + BN + ReLU layers (gather form, no float atomics on features) ----
  const float* gs[2] = {g1, g2};
  const float* bs[2] = {be1, be2};
  for (int layer = 0; layer < 2; ++layer){
    hipMemsetAsync(csum, 0, 1024*sizeof(float), stream); // csum+csq contiguous
    gin_gather_kernel<<<N_NODES/GN, 128, 0, stream>>>(h, rowstart, csr, h2, csum, csq);
    bn_relu_kernel<<<(N_NODES*(D/4)+255)/256, 256, 0, stream>>>(h2, h, csum, csq, gs[layer], bs[layer]);
  }

  // ---- per-graph mean readout ----
  hipMemsetAsync(qemb, 0, ((size_t)B*D + 64)*sizeof(float), stream); // qemb+gcnt contiguous
  readout_kernel<<<N_NODES/RO_ROWS, 256, 0, stream>>>(h, n2g, qemb, gcnt);

  // ---- MLP head ----
  hipMemsetAsync(s1, 0, 6*256*sizeof(float), stream); // s1..q3 contiguous
  fc1_kernel<<<NROW/FC_ROWS, 256, 0, stream>>>(qemb, gcnt, pg_emb, neigh, W_fc, b_fc, G1, s1, q1);
  fc_mid_kernel<<<NROW/FC_ROWS, 256, 0, stream>>>(G1, s1, q1, gb,  bb,  W_fc2, b_fc2, G2, s2, q2);
  fc_mid_kernel<<<NROW/FC_ROWS, 256, 0, stream>>>(G2, s2, q2, gb2, bb2, W_fc3, b_fc3, G3, s3, q3);
  final_kernel<<<(NROW+3)/4, 256, 0, stream>>>(G3, s3, q3, gb3, bb3, W_fc4, b_fc4, out);
}

// Round 3
// 354.453 us; speedup vs baseline: 7.0167x; 2.4417x over previous
//
#include <hip/hip_runtime.h>
#include <hip/hip_bf16.h>
#include <math.h>

#define N_NODES 10000
#define N_EDGES 160000
#define D 512
#define DIN 20
#define B 64
#define KC 10
#define DH 256
#define NROW (B*KC)   // 640
#define BN_EPS 1e-5f

__device__ __forceinline__ void f4acc(float4& a, const float4 v){
  a.x += v.x; a.y += v.y; a.z += v.z; a.w += v.w;
}

// ---------------- degree histogram (int) ----------------
__global__ void deg_kernel(const int* __restrict__ dst, int* __restrict__ degi, int E){
  int i = blockIdx.x*blockDim.x + threadIdx.x;
  if (i < E) atomicAdd(&degi[dst[i]], 1);
}

// ---------------- single-block scan over degrees + zero the accumulator region ----------------
__global__ void scan_kernel(const int* __restrict__ degi, int* __restrict__ rowstart,
                            int* __restrict__ cursor, float* __restrict__ zbuf, int zcount){
  __shared__ int part[256];
  int t = threadIdx.x;
  for (int i = t; i < zcount; i += 256) zbuf[i] = 0.0f;
  const int PER = (N_NODES + 255)/256; // 40
  int base = t*PER;
  int s = 0;
  for (int i = 0; i < PER; ++i){
    int idx = base+i;
    if (idx < N_NODES) s += degi[idx];
  }
  part[t] = s;
  __syncthreads();
  for (int off = 1; off < 256; off <<= 1){
    int v = (t >= off) ? part[t-off] : 0;
    __syncthreads();
    part[t] += v;
    __syncthreads();
  }
  int run = (t > 0) ? part[t-1] : 0;
  for (int i = 0; i < PER; ++i){
    int idx = base+i;
    if (idx < N_NODES){
      rowstart[idx] = run; cursor[idx] = run; run += degi[idx];
    }
  }
  if (t == 255) rowstart[N_NODES] = run;
}

// ---------------- CSR fill: csr[pos] = src, bucketed by dst ----------------
__global__ void fill_kernel(const int* __restrict__ src, const int* __restrict__ dst,
                            int* __restrict__ cursor, int* __restrict__ csr, int E){
  int i = blockIdx.x*blockDim.x + threadIdx.x;
  if (i < E){
    int p = atomicAdd(&cursor[dst[i]], 1);
    csr[p] = src[i];
  }
}

// ---------------- graph segment boundaries (n2g is sorted) ----------------
__global__ void gbounds_kernel(const int* __restrict__ n2g, int* __restrict__ gstart){
  int g = threadIdx.x;
  if (g > B) return;
  int lo = 0, hi = N_NODES;
  while (lo < hi){ int mid = (lo+hi)>>1; if (n2g[mid] < g) lo = mid+1; else hi = mid; }
  gstart[g] = lo;
}

// ---------------- h = x @ W_init + b_init ----------------
__global__ void init_mm_kernel(const float* __restrict__ x, const float* __restrict__ W,
                               const float* __restrict__ b, float* __restrict__ h){
  __shared__ float xs[DIN];
  int row = blockIdx.x;
  int t = threadIdx.x;
  if (t < DIN) xs[t] = x[row*DIN + t];
  __syncthreads();
  #pragma unroll
  for (int half = 0; half < 2; ++half){
    int col = t + half*256;
    float acc = b[col];
    #pragma unroll
    for (int k = 0; k < DIN; ++k) acc += xs[k]*W[k*D+col];
    h[(size_t)row*D + col] = acc;
  }
}

// ---------------- GIN gather: wave-per-node, 8 loads in flight ----------------
#define GWAVES 4
#define NPW 4
#define NWAVETOT (N_NODES/NPW)   // 2500
__global__ __launch_bounds__(256, 2)
void gin_gather_kernel(const float* __restrict__ h,
                       const int* __restrict__ rowstart,
                       const int* __restrict__ csr,
                       float* __restrict__ h2,
                       float* __restrict__ csum, float* __restrict__ csq){
  __shared__ float red[GWAVES][1024];
  int lane = threadIdx.x & 63;
  int wave = threadIdx.x >> 6;
  int wid  = blockIdx.x*GWAVES + wave;   // 0..2499
  const float4* h4 = (const float4*)h;
  float4 sA = make_float4(0,0,0,0), sB = make_float4(0,0,0,0);
  float4 qA = make_float4(0,0,0,0), qB = make_float4(0,0,0,0);
  for (int nn = 0; nn < NPW; ++nn){
    int node = wid + nn*NWAVETOT;
    int start = rowstart[node], end = rowstart[node+1];
    float4 aA = make_float4(0,0,0,0), aB = make_float4(0,0,0,0);
    float4 bA = make_float4(0,0,0,0), bB = make_float4(0,0,0,0);
    for (int base = start; base < end; base += 64){
      int cnt = end - base; if (cnt > 64) cnt = 64;
      int myidx = (lane < cnt) ? csr[base+lane] : 0;
      int j = 0;
      for (; j+4 <= cnt; j += 4){
        int i0 = __shfl(myidx, j,   64);
        int i1 = __shfl(myidx, j+1, 64);
        int i2 = __shfl(myidx, j+2, 64);
        int i3 = __shfl(myidx, j+3, 64);
        const float4* r0 = h4 + (size_t)i0*(D/4);
        const float4* r1 = h4 + (size_t)i1*(D/4);
        const float4* r2 = h4 + (size_t)i2*(D/4);
        const float4* r3 = h4 + (size_t)i3*(D/4);
        float4 va0 = r0[lane], vb0 = r0[lane+64];
        float4 va1 = r1[lane], vb1 = r1[lane+64];
        float4 va2 = r2[lane], vb2 = r2[lane+64];
        float4 va3 = r3[lane], vb3 = r3[lane+64];
        f4acc(aA, va0); f4acc(bA, vb0);
        f4acc(aB, va1); f4acc(bB, vb1);
        f4acc(aA, va2); f4acc(bA, vb2);
        f4acc(aB, va3); f4acc(bB, vb3);
      }
      for (; j < cnt; ++j){
        int i0 = __shfl(myidx, j, 64);
        const float4* r0 = h4 + (size_t)i0*(D/4);
        float4 va = r0[lane], vb = r0[lane+64];
        f4acc(aA, va); f4acc(bA, vb);
      }
    }
    float inv = 1.0f/fmaxf((float)(end-start), 1.0f);
    float4 hva = h4[(size_t)node*(D/4) + lane];
    float4 hvb = h4[(size_t)node*(D/4) + 64 + lane];
    float4 oA, oB;
    oA.x = hva.x + (aA.x+aB.x)*inv;  oA.y = hva.y + (aA.y+aB.y)*inv;
    oA.z = hva.z + (aA.z+aB.z)*inv;  oA.w = hva.w + (aA.w+aB.w)*inv;
    oB.x = hvb.x + (bA.x+bB.x)*inv;  oB.y = hvb.y + (bA.y+bB.y)*inv;
    oB.z = hvb.z + (bA.z+bB.z)*inv;  oB.w = hvb.w + (bA.w+bB.w)*inv;
    ((float4*)(h2 + (size_t)node*D))[lane]      = oA;
    ((float4*)(h2 + (size_t)node*D))[lane + 64] = oB;
    f4acc(sA, oA); f4acc(sB, oB);
    qA.x += oA.x*oA.x; qA.y += oA.y*oA.y; qA.z += oA.z*oA.z; qA.w += oA.w*oA.w;
    qB.x += oB.x*oB.x; qB.y += oB.y*oB.y; qB.z += oB.z*oB.z; qB.w += oB.w*oB.w;
  }
  // stage per-wave stats: [0,256)=sum lo cols, [256,512)=sum hi, [512,768)=sq lo, [768,1024)=sq hi
  float* my = red[wave];
  int c = 4*lane;
  my[c+0]=sA.x; my[c+1]=sA.y; my[c+2]=sA.z; my[c+3]=sA.w;
  my[256+c+0]=sB.x; my[256+c+1]=sB.y; my[256+c+2]=sB.z; my[256+c+3]=sB.w;
  my[512+c+0]=qA.x; my[512+c+1]=qA.y; my[512+c+2]=qA.z; my[512+c+3]=qA.w;
  my[768+c+0]=qB.x; my[768+c+1]=qB.y; my[768+c+2]=qB.z; my[768+c+3]=qB.w;
  __syncthreads();
  for (int e = threadIdx.x; e < 1024; e += 256){
    float v = red[0][e] + red[1][e] + red[2][e] + red[3][e];
    if (e < 512) atomicAdd(&csum[e], v);
    else         atomicAdd(&csq[e-512], v);
  }
}

// ---------------- h = relu(BN(h2)) ----------------
__global__ void bn_relu_kernel(const float* __restrict__ in, float* __restrict__ out,
                               const float* __restrict__ csum, const float* __restrict__ csq,
                               const float* __restrict__ gamma, const float* __restrict__ beta){
  int i = blockIdx.x*blockDim.x + threadIdx.x; // float4 index
  const int total = N_NODES*(D/4);
  if (i >= total) return;
  int c = (i & (D/4 - 1))*4;
  float4 v = ((const float4*)in)[i];
  const float invN = 1.0f/(float)N_NODES;
  float4 o;
  float* vp = &v.x; float* op = &o.x;
  #pragma unroll
  for (int j=0;j<4;++j){
    float mu = csum[c+j]*invN;
    float var = csq[c+j]*invN - mu*mu;
    float rs = rsqrtf(var + BN_EPS);
    op[j] = fmaxf((vp[j]-mu)*rs*gamma[c+j] + beta[c+j], 0.0f);
  }
  ((float4*)out)[i] = o;
}

// ---------------- per-graph mean readout: segment reduce (n2g sorted) ----------------
__global__ void readout_kernel(const float* __restrict__ h, const int* __restrict__ gstart,
                               float* __restrict__ qemb){
  int g = blockIdx.x, chunk = blockIdx.y;
  int t = threadIdx.x;
  int s = gstart[g], e = gstart[g+1];
  int rows = e - s;
  int per = (rows + 7)/8;
  int r0 = s + chunk*per;
  int r1 = r0 + per; if (r1 > e) r1 = e;
  if (r0 >= r1) return;
  float a0=0.f, a1=0.f, b0=0.f, b1=0.f;
  int r = r0;
  for (; r+3 < r1; r += 4){
    a0 += h[(size_t)r*D + t];         b0 += h[(size_t)r*D + t + 256];
    a1 += h[(size_t)(r+1)*D + t];     b1 += h[(size_t)(r+1)*D + t + 256];
    a0 += h[(size_t)(r+2)*D + t];     b0 += h[(size_t)(r+2)*D + t + 256];
    a1 += h[(size_t)(r+3)*D + t];     b1 += h[(size_t)(r+3)*D + t + 256];
  }
  for (; r < r1; ++r){
    a0 += h[(size_t)r*D + t];         b0 += h[(size_t)r*D + t + 256];
  }
  atomicAdd(&qemb[(size_t)g*D + t],       a0 + a1);
  atomicAdd(&qemb[(size_t)g*D + t + 256], b0 + b1);
}

// ---------------- FC1: [640,1536]@[1536,256] + bias, accumulate stats ----------------
#define FC_ROWS 8
__global__ void fc1_kernel(const float* __restrict__ qemb, const int* __restrict__ gstart,
                           const float* __restrict__ pg, const float* __restrict__ neigh,
                           const float* __restrict__ W, const float* __restrict__ bias,
                           float* __restrict__ out, float* __restrict__ s, float* __restrict__ q){
  __shared__ float brow[FC_ROWS][3*D];
  int t = threadIdx.x;
  int r0 = blockIdx.x*FC_ROWS;
  for (int rr=0; rr<FC_ROWS; ++rr){
    int r = r0+rr;
    int g = r/KC, k = r - g*KC;
    float invc = 1.0f/fmaxf((float)(gstart[g+1]-gstart[g]), 1.0f);
    for (int j = t; j < 3*D; j += 256){
      float v;
      if (j < D)        v = qemb[(size_t)g*D+j]*invc;
      else if (j < 2*D) v = pg[(size_t)g*D + (j-D)];
      else              v = neigh[((size_t)g*KC + k)*D + (j-2*D)];
      brow[rr][j] = v;
    }
  }
  __syncthreads();
  int col = t;
  float acc[FC_ROWS];
  #pragma unroll
  for (int rr=0;rr<FC_ROWS;++rr) acc[rr] = bias[col];
  for (int kk=0; kk<3*D; ++kk){
    float w = W[kk*DH + col];
    #pragma unroll
    for (int rr=0;rr<FC_ROWS;++rr) acc[rr] += brow[rr][kk]*w;
  }
  float ls=0.f,lq=0.f;
  #pragma unroll
  for (int rr=0;rr<FC_ROWS;++rr){
    out[(size_t)(r0+rr)*DH + col] = acc[rr];
    ls += acc[rr]; lq += acc[rr]*acc[rr];
  }
  atomicAdd(&s[col], ls); atomicAdd(&q[col], lq);
}

// ---------------- FC mid: BN(prev)+relu staged, @[256,256] + bias, stats ----------------
__global__ void fc_mid_kernel(const float* __restrict__ in, const float* __restrict__ ps,
                              const float* __restrict__ pq, const float* __restrict__ gamma,
                              const float* __restrict__ beta,
                              const float* __restrict__ W, const float* __restrict__ bias,
                              float* __restrict__ out, float* __restrict__ s, float* __restrict__ q){
  __shared__ float row[FC_ROWS][DH];
  int t = threadIdx.x;
  int r0 = blockIdx.x*FC_ROWS;
  const float invM = 1.0f/(float)NROW;
  float mu = ps[t]*invM;
  float var = pq[t]*invM - mu*mu;
  float rs = rsqrtf(var+BN_EPS);
  float ga = gamma[t], be = beta[t];
  for (int rr=0; rr<FC_ROWS; ++rr){
    float v = in[(size_t)(r0+rr)*DH + t];
    row[rr][t] = fmaxf((v-mu)*rs*ga + be, 0.0f);
  }
  __syncthreads();
  float acc[FC_ROWS];
  #pragma unroll
  for (int rr=0;rr<FC_ROWS;++rr) acc[rr]=bias[t];
  for (int kk=0; kk<DH; ++kk){
    float w = W[kk*DH + t];
    #pragma unroll
    for (int rr=0;rr<FC_ROWS;++rr) acc[rr] += row[rr][kk]*w;
  }
  float ls=0.f,lq=0.f;
  #pragma unroll
  for (int rr=0;rr<FC_ROWS;++rr){
    out[(size_t)(r0+rr)*DH+t]=acc[rr];
    ls+=acc[rr]; lq+=acc[rr]*acc[rr];
  }
  atomicAdd(&s[t],ls); atomicAdd(&q[t],lq);
}

// ---------------- final: BN3+relu, dot W_fc4, sigmoid ----------------
__global__ void final_kernel(const float* __restrict__ G3, const float* __restrict__ ps,
                             const float* __restrict__ pq, const float* __restrict__ gamma,
                             const float* __restrict__ beta,
                             const float* __restrict__ w4, const float* __restrict__ b4,
                             float* __restrict__ out){
  int wave = threadIdx.x>>6, lane = threadIdx.x&63;
  int r = blockIdx.x*4 + wave;
  if (r >= NROW) return;
  const float invM = 1.0f/(float)NROW;
  float sum = 0.f;
  #pragma unroll
  for (int j=0;j<4;++j){
    int c = lane + 64*j;
    float mu = ps[c]*invM;
    float var = pq[c]*invM - mu*mu;
    float rs = rsqrtf(var+BN_EPS);
    float v = G3[(size_t)r*DH + c];
    v = fmaxf((v-mu)*rs*gamma[c]+beta[c], 0.0f);
    sum += v*w4[c];
  }
  #pragma unroll
  for (int off=32; off>0; off>>=1) sum += __shfl_down(sum, off, 64);
  if (lane==0){
    float z = sum + b4[0];
    out[r] = 1.0f/(1.0f + expf(-z));
  }
}

extern "C" void kernel_launch(void* const* d_in, const int* in_sizes, int n_in,
                              void* d_out, int out_size, void* d_ws, size_t ws_size,
                              hipStream_t stream) {
  const float* x        = (const float*)d_in[0];
  const float* pg_emb   = (const float*)d_in[1];
  const float* neigh    = (const float*)d_in[2];
  const float* W_init   = (const float*)d_in[3];
  const float* b_init   = (const float*)d_in[4];
  const float* g1       = (const float*)d_in[5];
  const float* be1      = (const float*)d_in[6];
  const float* g2       = (const float*)d_in[7];
  const float* be2      = (const float*)d_in[8];
  const float* W_fc     = (const float*)d_in[9];
  const float* b_fc     = (const float*)d_in[10];
  const float* W_fc2    = (const float*)d_in[11];
  const float* b_fc2    = (const float*)d_in[12];
  const float* W_fc3    = (const float*)d_in[13];
  const float* b_fc3    = (const float*)d_in[14];
  const float* W_fc4    = (const float*)d_in[15];
  const float* b_fc4    = (const float*)d_in[16];
  const float* gb       = (const float*)d_in[17];
  const float* bb       = (const float*)d_in[18];
  const float* gb2      = (const float*)d_in[19];
  const float* bb2      = (const float*)d_in[20];
  const float* gb3      = (const float*)d_in[21];
  const float* bb3      = (const float*)d_in[22];
  const int*   esrc     = (const int*)d_in[23];
  const int*   edst     = (const int*)d_in[24];
  const int*   n2g      = (const int*)d_in[25];
  float* out = (float*)d_out;

  float* ws = (float*)d_ws;
  size_t off = 0;
  float* h    = ws + off; off += (size_t)N_NODES*D;
  float* h2   = ws + off; off += (size_t)N_NODES*D;
  // ---- contiguous zeroed-by-scan region ----
  float* zbase = ws + off;
  float* csum1 = ws + off; off += 512;
  float* csq1  = ws + off; off += 512;
  float* csum2 = ws + off; off += 512;
  float* csq2  = ws + off; off += 512;
  float* s1    = ws + off; off += 256;
  float* q1    = ws + off; off += 256;
  float* s2    = ws + off; off += 256;
  float* q2    = ws + off; off += 256;
  float* s3    = ws + off; off += 256;
  float* q3    = ws + off; off += 256;
  float* qemb  = ws + off; off += (size_t)B*D;
  int zcount = (int)((ws + off) - zbase);
  // ---- end zero region ----
  float* G1   = ws + off; off += (size_t)NROW*DH;
  float* G2   = ws + off; off += (size_t)NROW*DH;
  float* G3   = ws + off; off += (size_t)NROW*DH;
  int* degi     = (int*)(ws + off); off += N_NODES;
  int* rowstart = (int*)(ws + off); off += N_NODES + 1;
  int* cursor   = (int*)(ws + off); off += N_NODES;
  int* csr      = (int*)(ws + off); off += N_EDGES;
  int* gstart   = (int*)(ws + off); off += B + 1;

  // ---- build CSR + graph bounds ----
  hipMemsetAsync(degi, 0, (size_t)N_NODES*sizeof(int), stream);
  deg_kernel<<<(N_EDGES+255)/256, 256, 0, stream>>>(edst, degi, N_EDGES);
  scan_kernel<<<1, 256, 0, stream>>>(degi, rowstart, cursor, zbase, zcount);
  fill_kernel<<<(N_EDGES+255)/256, 256, 0, stream>>>(esrc, edst, cursor, csr, N_EDGES);
  gbounds_kernel<<<1, 128, 0, stream>>>(n2g, gstart);

  // ---- initial projection ----
  init_mm_kernel<<<N_NODES, 256, 0, stream>>>(x, W_init, b_init, h);

  // ---- two GIN(mean) + BN + ReLU layers ----
  gin_gather_kernel<<<NWAVETOT/GWAVES, 256, 0, stream>>>(h, rowstart, csr, h2, csum1, csq1);
  bn_relu_kernel<<<(N_NODES*(D/4)+255)/256, 256, 0, stream>>>(h2, h, csum1, csq1, g1, be1);
  gin_gather_kernel<<<NWAVETOT/GWAVES, 256, 0, stream>>>(h, rowstart, csr, h2, csum2, csq2);
  bn_relu_kernel<<<(N_NODES*(D/4)+255)/256, 256, 0, stream>>>(h2, h, csum2, csq2, g2, be2);

  // ---- per-graph mean readout (segment reduce over sorted n2g) ----
  readout_kernel<<<dim3(B, 8), 256, 0, stream>>>(h, gstart, qemb);

  // ---- MLP head ----
  fc1_kernel<<<NROW/FC_ROWS, 256, 0, stream>>>(qemb, gstart, pg_emb, neigh, W_fc, b_fc, G1, s1, q1);
  fc_mid_kernel<<<NROW/FC_ROWS, 256, 0, stream>>>(G1, s1, q1, gb,  bb,  W_fc2, b_fc2, G2, s2, q2);
  fc_mid_kernel<<<NROW/FC_ROWS, 256, 0, stream>>>(G2, s2, q2, gb2, bb2, W_fc3, b_fc3, G3, s3, q3);
  final_kernel<<<(NROW+3)/4, 256, 0, stream>>>(G3, s3, q3, gb3, bb3, W_fc4, b_fc4, out);
}

// Round 4
// 290.812 us; speedup vs baseline: 8.5523x; 1.2188x over previous
//
#include <hip/hip_runtime.h>
#include <hip/hip_bf16.h>
#include <math.h>

#define N_NODES 10000
#define N_EDGES 160000
#define D 512
#define DIN 20
#define B 64
#define KC 10
#define DH 256
#define NROW (B*KC)   // 640
#define BN_EPS 1e-5f

__device__ __forceinline__ void f4acc(float4& a, const float4 v){
  a.x += v.x; a.y += v.y; a.z += v.z; a.w += v.w;
}

// ---------------- degree histogram (int) ----------------
__global__ void deg_kernel(const int* __restrict__ dst, int* __restrict__ degi, int E){
  int i = blockIdx.x*blockDim.x + threadIdx.x;
  if (i < E) atomicAdd(&degi[dst[i]], 1);
}

// ---------------- single-block scan over degrees + zero the accumulator region ----------------
__global__ void scan_kernel(const int* __restrict__ degi, int* __restrict__ rowstart,
                            int* __restrict__ cursor, float* __restrict__ zbuf, int zcount){
  __shared__ int part[256];
  int t = threadIdx.x;
  for (int i = t; i < zcount; i += 256) zbuf[i] = 0.0f;
  const int PER = (N_NODES + 255)/256; // 40
  int base = t*PER;
  int s = 0;
  for (int i = 0; i < PER; ++i){
    int idx = base+i;
    if (idx < N_NODES) s += degi[idx];
  }
  part[t] = s;
  __syncthreads();
  for (int off = 1; off < 256; off <<= 1){
    int v = (t >= off) ? part[t-off] : 0;
    __syncthreads();
    part[t] += v;
    __syncthreads();
  }
  int run = (t > 0) ? part[t-1] : 0;
  for (int i = 0; i < PER; ++i){
    int idx = base+i;
    if (idx < N_NODES){
      rowstart[idx] = run; cursor[idx] = run; run += degi[idx];
    }
  }
  if (t == 255) rowstart[N_NODES] = run;
}

// ---------------- CSR fill: csr[pos] = src, bucketed by dst ----------------
__global__ void fill_kernel(const int* __restrict__ src, const int* __restrict__ dst,
                            int* __restrict__ cursor, int* __restrict__ csr, int E){
  int i = blockIdx.x*blockDim.x + threadIdx.x;
  if (i < E){
    int p = atomicAdd(&cursor[dst[i]], 1);
    csr[p] = src[i];
  }
}

// ---------------- graph segment boundaries (n2g is sorted) ----------------
__global__ void gbounds_kernel(const int* __restrict__ n2g, int* __restrict__ gstart){
  int g = threadIdx.x;
  if (g > B) return;
  int lo = 0, hi = N_NODES;
  while (lo < hi){ int mid = (lo+hi)>>1; if (n2g[mid] < g) lo = mid+1; else hi = mid; }
  gstart[g] = lo;
}

// ---------------- h = x @ W_init + b_init  (W staged in LDS, 8 rows/block) ----------------
#define IM_ROWS 8
__global__ __launch_bounds__(256)
void init_mm_kernel(const float* __restrict__ x, const float* __restrict__ W,
                    const float* __restrict__ b, float* __restrict__ h){
  __shared__ float Ws[DIN][D];        // 40 KB
  __shared__ float xs[IM_ROWS][DIN];
  int t = threadIdx.x;
  int r0 = blockIdx.x*IM_ROWS;
  for (int i = t; i < DIN*D; i += 256) Ws[i >> 9][i & (D-1)] = W[i];
  for (int i = t; i < IM_ROWS*DIN; i += 256) xs[i/DIN][i%DIN] = x[(size_t)r0*DIN + i];
  __syncthreads();
  float b0 = b[t], b1 = b[t+256];
  for (int rr = 0; rr < IM_ROWS; ++rr){
    float a0 = b0, a1 = b1;
    #pragma unroll
    for (int k = 0; k < DIN; ++k){
      float xv = xs[rr][k];
      a0 += xv*Ws[k][t];
      a1 += xv*Ws[k][t+256];
    }
    h[(size_t)(r0+rr)*D + t]       = a0;
    h[(size_t)(r0+rr)*D + t + 256] = a1;
  }
}

// ---------------- GIN gather: wave-per-node, 8 loads in flight ----------------
#define GWAVES 4
#define NPW 4
#define NWAVETOT (N_NODES/NPW)   // 2500
__global__ __launch_bounds__(256, 2)
void gin_gather_kernel(const float* __restrict__ h,
                       const int* __restrict__ rowstart,
                       const int* __restrict__ csr,
                       float* __restrict__ h2,
                       float* __restrict__ csum, float* __restrict__ csq){
  __shared__ float red[GWAVES][1024];
  int lane = threadIdx.x & 63;
  int wave = threadIdx.x >> 6;
  int wid  = blockIdx.x*GWAVES + wave;   // 0..2499
  const float4* h4 = (const float4*)h;
  float4 sA = make_float4(0,0,0,0), sB = make_float4(0,0,0,0);
  float4 qA = make_float4(0,0,0,0), qB = make_float4(0,0,0,0);
  for (int nn = 0; nn < NPW; ++nn){
    int node = wid + nn*NWAVETOT;
    int start = rowstart[node], end = rowstart[node+1];
    float4 aA = make_float4(0,0,0,0), aB = make_float4(0,0,0,0);
    float4 bA = make_float4(0,0,0,0), bB = make_float4(0,0,0,0);
    for (int base = start; base < end; base += 64){
      int cnt = end - base; if (cnt > 64) cnt = 64;
      int myidx = (lane < cnt) ? csr[base+lane] : 0;
      int j = 0;
      for (; j+4 <= cnt; j += 4){
        int i0 = __shfl(myidx, j,   64);
        int i1 = __shfl(myidx, j+1, 64);
        int i2 = __shfl(myidx, j+2, 64);
        int i3 = __shfl(myidx, j+3, 64);
        const float4* r0 = h4 + (size_t)i0*(D/4);
        const float4* r1 = h4 + (size_t)i1*(D/4);
        const float4* r2 = h4 + (size_t)i2*(D/4);
        const float4* r3 = h4 + (size_t)i3*(D/4);
        float4 va0 = r0[lane], vb0 = r0[lane+64];
        float4 va1 = r1[lane], vb1 = r1[lane+64];
        float4 va2 = r2[lane], vb2 = r2[lane+64];
        float4 va3 = r3[lane], vb3 = r3[lane+64];
        f4acc(aA, va0); f4acc(bA, vb0);
        f4acc(aB, va1); f4acc(bB, vb1);
        f4acc(aA, va2); f4acc(bA, vb2);
        f4acc(aB, va3); f4acc(bB, vb3);
      }
      for (; j < cnt; ++j){
        int i0 = __shfl(myidx, j, 64);
        const float4* r0 = h4 + (size_t)i0*(D/4);
        float4 va = r0[lane], vb = r0[lane+64];
        f4acc(aA, va); f4acc(bA, vb);
      }
    }
    float inv = 1.0f/fmaxf((float)(end-start), 1.0f);
    float4 hva = h4[(size_t)node*(D/4) + lane];
    float4 hvb = h4[(size_t)node*(D/4) + 64 + lane];
    float4 oA, oB;
    oA.x = hva.x + (aA.x+aB.x)*inv;  oA.y = hva.y + (aA.y+aB.y)*inv;
    oA.z = hva.z + (aA.z+aB.z)*inv;  oA.w = hva.w + (aA.w+aB.w)*inv;
    oB.x = hvb.x + (bA.x+bB.x)*inv;  oB.y = hvb.y + (bA.y+bB.y)*inv;
    oB.z = hvb.z + (bA.z+bB.z)*inv;  oB.w = hvb.w + (bA.w+bB.w)*inv;
    ((float4*)(h2 + (size_t)node*D))[lane]      = oA;
    ((float4*)(h2 + (size_t)node*D))[lane + 64] = oB;
    f4acc(sA, oA); f4acc(sB, oB);
    qA.x += oA.x*oA.x; qA.y += oA.y*oA.y; qA.z += oA.z*oA.z; qA.w += oA.w*oA.w;
    qB.x += oB.x*oB.x; qB.y += oB.y*oB.y; qB.z += oB.z*oB.z; qB.w += oB.w*oB.w;
  }
  float* my = red[wave];
  int c = 4*lane;
  my[c+0]=sA.x; my[c+1]=sA.y; my[c+2]=sA.z; my[c+3]=sA.w;
  my[256+c+0]=sB.x; my[256+c+1]=sB.y; my[256+c+2]=sB.z; my[256+c+3]=sB.w;
  my[512+c+0]=qA.x; my[512+c+1]=qA.y; my[512+c+2]=qA.z; my[512+c+3]=qA.w;
  my[768+c+0]=qB.x; my[768+c+1]=qB.y; my[768+c+2]=qB.z; my[768+c+3]=qB.w;
  __syncthreads();
  for (int e = threadIdx.x; e < 1024; e += 256){
    float v = red[0][e] + red[1][e] + red[2][e] + red[3][e];
    if (e < 512) atomicAdd(&csum[e], v);
    else         atomicAdd(&csq[e-512], v);
  }
}

// ---------------- h = relu(BN(h2)) ----------------
__global__ void bn_relu_kernel(const float* __restrict__ in, float* __restrict__ out,
                               const float* __restrict__ csum, const float* __restrict__ csq,
                               const float* __restrict__ gamma, const float* __restrict__ beta){
  int i = blockIdx.x*blockDim.x + threadIdx.x; // float4 index
  const int total = N_NODES*(D/4);
  if (i >= total) return;
  int c = (i & (D/4 - 1))*4;
  float4 v = ((const float4*)in)[i];
  const float invN = 1.0f/(float)N_NODES;
  float4 o;
  float* vp = &v.x; float* op = &o.x;
  #pragma unroll
  for (int j=0;j<4;++j){
    float mu = csum[c+j]*invN;
    float var = csq[c+j]*invN - mu*mu;
    float rs = rsqrtf(var + BN_EPS);
    op[j] = fmaxf((vp[j]-mu)*rs*gamma[c+j] + beta[c+j], 0.0f);
  }
  ((float4*)out)[i] = o;
}

// ---------------- per-graph mean readout: segment reduce (n2g sorted) ----------------
__global__ void readout_kernel(const float* __restrict__ h, const int* __restrict__ gstart,
                               float* __restrict__ qemb){
  int g = blockIdx.x, chunk = blockIdx.y;
  int t = threadIdx.x;
  int s = gstart[g], e = gstart[g+1];
  int rows = e - s;
  int per = (rows + 7)/8;
  int r0 = s + chunk*per;
  int r1 = r0 + per; if (r1 > e) r1 = e;
  if (r0 >= r1) return;
  float a0=0.f, a1=0.f, b0=0.f, b1=0.f;
  int r = r0;
  for (; r+3 < r1; r += 4){
    a0 += h[(size_t)r*D + t];         b0 += h[(size_t)r*D + t + 256];
    a1 += h[(size_t)(r+1)*D + t];     b1 += h[(size_t)(r+1)*D + t + 256];
    a0 += h[(size_t)(r+2)*D + t];     b0 += h[(size_t)(r+2)*D + t + 256];
    a1 += h[(size_t)(r+3)*D + t];     b1 += h[(size_t)(r+3)*D + t + 256];
  }
  for (; r < r1; ++r){
    a0 += h[(size_t)r*D + t];         b0 += h[(size_t)r*D + t + 256];
  }
  atomicAdd(&qemb[(size_t)g*D + t],       a0 + a1);
  atomicAdd(&qemb[(size_t)g*D + t + 256], b0 + b1);
}

// ---------------- FC1 partials: [640,1536]@[1536,256], K split 6x256 ----------------
#define F1_ROWS 8
#define F1_KS 256
#define F1_NS 6
__global__ __launch_bounds__(256)
void fc1_partial_kernel(const float* __restrict__ qemb, const int* __restrict__ gstart,
                        const float* __restrict__ pg, const float* __restrict__ neigh,
                        const float* __restrict__ W, float* __restrict__ part){
  __shared__ float brow[F1_ROWS][F1_KS];
  int t = threadIdx.x;
  int r0 = blockIdx.x*F1_ROWS;
  int k0 = blockIdx.y*F1_KS;
  for (int rr=0; rr<F1_ROWS; ++rr){
    int r = r0+rr;
    int g = r/KC, k = r - g*KC;
    int j = k0 + t;
    float v;
    if (j < D){
      float invc = 1.0f/fmaxf((float)(gstart[g+1]-gstart[g]), 1.0f);
      v = qemb[(size_t)g*D + j]*invc;
    } else if (j < 2*D){
      v = pg[(size_t)g*D + (j-D)];
    } else {
      v = neigh[((size_t)g*KC + k)*D + (j-2*D)];
    }
    brow[rr][t] = v;
  }
  __syncthreads();
  float acc[F1_ROWS] = {0.f,0.f,0.f,0.f,0.f,0.f,0.f,0.f};
  #pragma unroll 4
  for (int kk=0; kk<F1_KS; ++kk){
    float w = W[(size_t)(k0+kk)*DH + t];
    #pragma unroll
    for (int rr=0; rr<F1_ROWS; ++rr) acc[rr] += brow[rr][kk]*w;
  }
  for (int rr=0; rr<F1_ROWS; ++rr)
    part[((size_t)blockIdx.y*NROW + r0+rr)*DH + t] = acc[rr];
}

// ---------------- reduce partials + bias, write out, accumulate BN stats ----------------
__global__ __launch_bounds__(256)
void reduce_stats_kernel(const float* __restrict__ part, const float* __restrict__ bias,
                         float* __restrict__ out, float* __restrict__ s, float* __restrict__ q,
                         int nslice){
  int t = threadIdx.x;            // col
  int r0 = blockIdx.x*8;
  float bval = bias[t];
  float ls = 0.f, lq = 0.f;
  for (int rr = 0; rr < 8; ++rr){
    int r = r0+rr;
    float acc = bval;
    for (int sl = 0; sl < nslice; ++sl) acc += part[((size_t)sl*NROW + r)*DH + t];
    out[(size_t)r*DH + t] = acc;
    ls += acc; lq += acc*acc;
  }
  atomicAdd(&s[t], ls); atomicAdd(&q[t], lq);
}

// ---------------- FC mid partials: BN(prev)+relu staged, K split 2x128 ----------------
#define FM_ROWS 4
#define FM_KS 128
#define FM_NS 2
__global__ __launch_bounds__(256)
void fc_mid_partial_kernel(const float* __restrict__ in, const float* __restrict__ ps,
                           const float* __restrict__ pq, const float* __restrict__ gamma,
                           const float* __restrict__ beta, const float* __restrict__ W,
                           float* __restrict__ part){
  __shared__ float row[FM_ROWS][FM_KS];
  int t = threadIdx.x;
  int r0 = blockIdx.x*FM_ROWS;
  int k0 = blockIdx.y*FM_KS;
  const float invM = 1.0f/(float)NROW;
  #pragma unroll
  for (int i = 0; i < 2; ++i){
    int idx = t + i*256;          // 0..511
    int rr = idx >> 7, kk = idx & 127;
    int c = k0 + kk;
    float mu = ps[c]*invM;
    float var = pq[c]*invM - mu*mu;
    float rs = rsqrtf(var + BN_EPS);
    float v = in[(size_t)(r0+rr)*DH + c];
    row[rr][kk] = fmaxf((v-mu)*rs*gamma[c] + beta[c], 0.0f);
  }
  __syncthreads();
  float acc[FM_ROWS] = {0.f,0.f,0.f,0.f};
  #pragma unroll 4
  for (int kk=0; kk<FM_KS; ++kk){
    float w = W[(size_t)(k0+kk)*DH + t];
    #pragma unroll
    for (int rr=0; rr<FM_ROWS; ++rr) acc[rr] += row[rr][kk]*w;
  }
  for (int rr=0; rr<FM_ROWS; ++rr)
    part[((size_t)blockIdx.y*NROW + r0+rr)*DH + t] = acc[rr];
}

// ---------------- final: BN3+relu, dot W_fc4, sigmoid ----------------
__global__ void final_kernel(const float* __restrict__ G3, const float* __restrict__ ps,
                             const float* __restrict__ pq, const float* __restrict__ gamma,
                             const float* __restrict__ beta,
                             const float* __restrict__ w4, const float* __restrict__ b4,
                             float* __restrict__ out){
  int wave = threadIdx.x>>6, lane = threadIdx.x&63;
  int r = blockIdx.x*4 + wave;
  if (r >= NROW) return;
  const float invM = 1.0f/(float)NROW;
  float sum = 0.f;
  #pragma unroll
  for (int j=0;j<4;++j){
    int c = lane + 64*j;
    float mu = ps[c]*invM;
    float var = pq[c]*invM - mu*mu;
    float rs = rsqrtf(var+BN_EPS);
    float v = G3[(size_t)r*DH + c];
    v = fmaxf((v-mu)*rs*gamma[c]+beta[c], 0.0f);
    sum += v*w4[c];
  }
  #pragma unroll
  for (int off=32; off>0; off>>=1) sum += __shfl_down(sum, off, 64);
  if (lane==0){
    float z = sum + b4[0];
    out[r] = 1.0f/(1.0f + expf(-z));
  }
}

extern "C" void kernel_launch(void* const* d_in, const int* in_sizes, int n_in,
                              void* d_out, int out_size, void* d_ws, size_t ws_size,
                              hipStream_t stream) {
  const float* x        = (const float*)d_in[0];
  const float* pg_emb   = (const float*)d_in[1];
  const float* neigh    = (const float*)d_in[2];
  const float* W_init   = (const float*)d_in[3];
  const float* b_init   = (const float*)d_in[4];
  const float* g1       = (const float*)d_in[5];
  const float* be1      = (const float*)d_in[6];
  const float* g2       = (const float*)d_in[7];
  const float* be2      = (const float*)d_in[8];
  const float* W_fc     = (const float*)d_in[9];
  const float* b_fc     = (const float*)d_in[10];
  const float* W_fc2    = (const float*)d_in[11];
  const float* b_fc2    = (const float*)d_in[12];
  const float* W_fc3    = (const float*)d_in[13];
  const float* b_fc3    = (const float*)d_in[14];
  const float* W_fc4    = (const float*)d_in[15];
  const float* b_fc4    = (const float*)d_in[16];
  const float* gb       = (const float*)d_in[17];
  const float* bb       = (const float*)d_in[18];
  const float* gb2      = (const float*)d_in[19];
  const float* bb2      = (const float*)d_in[20];
  const float* gb3      = (const float*)d_in[21];
  const float* bb3      = (const float*)d_in[22];
  const int*   esrc     = (const int*)d_in[23];
  const int*   edst     = (const int*)d_in[24];
  const int*   n2g      = (const int*)d_in[25];
  float* out = (float*)d_out;

  float* ws = (float*)d_ws;
  size_t off = 0;
  float* h    = ws + off; off += (size_t)N_NODES*D;
  float* h2   = ws + off; off += (size_t)N_NODES*D;   // reused as `part` for the MLP head
  // ---- contiguous zeroed-by-scan region ----
  float* zbase = ws + off;
  float* csum1 = ws + off; off += 512;
  float* csq1  = ws + off; off += 512;
  float* csum2 = ws + off; off += 512;
  float* csq2  = ws + off; off += 512;
  float* s1    = ws + off; off += 256;
  float* q1    = ws + off; off += 256;
  float* s2    = ws + off; off += 256;
  float* q2    = ws + off; off += 256;
  float* s3    = ws + off; off += 256;
  float* q3    = ws + off; off += 256;
  float* qemb  = ws + off; off += (size_t)B*D;
  int zcount = (int)((ws + off) - zbase);
  // ---- end zero region ----
  float* G1   = ws + off; off += (size_t)NROW*DH;
  float* G2   = ws + off; off += (size_t)NROW*DH;
  float* G3   = ws + off; off += (size_t)NROW*DH;
  int* degi     = (int*)(ws + off); off += N_NODES;
  int* rowstart = (int*)(ws + off); off += N_NODES + 1;
  int* cursor   = (int*)(ws + off); off += N_NODES;
  int* csr      = (int*)(ws + off); off += N_EDGES;
  int* gstart   = (int*)(ws + off); off += B + 1;
  float* part = h2;  // MLP head partials (h2 is free after the GIN layers)

  // ---- build CSR + graph bounds ----
  hipMemsetAsync(degi, 0, (size_t)N_NODES*sizeof(int), stream);
  deg_kernel<<<(N_EDGES+255)/256, 256, 0, stream>>>(edst, degi, N_EDGES);
  scan_kernel<<<1, 256, 0, stream>>>(degi, rowstart, cursor, zbase, zcount);
  fill_kernel<<<(N_EDGES+255)/256, 256, 0, stream>>>(esrc, edst, cursor, csr, N_EDGES);
  gbounds_kernel<<<1, 128, 0, stream>>>(n2g, gstart);

  // ---- initial projection ----
  init_mm_kernel<<<N_NODES/IM_ROWS, 256, 0, stream>>>(x, W_init, b_init, h);

  // ---- two GIN(mean) + BN + ReLU layers ----
  gin_gather_kernel<<<NWAVETOT/GWAVES, 256, 0, stream>>>(h, rowstart, csr, h2, csum1, csq1);
  bn_relu_kernel<<<(N_NODES*(D/4)+255)/256, 256, 0, stream>>>(h2, h, csum1, csq1, g1, be1);
  gin_gather_kernel<<<NWAVETOT/GWAVES, 256, 0, stream>>>(h, rowstart, csr, h2, csum2, csq2);
  bn_relu_kernel<<<(N_NODES*(D/4)+255)/256, 256, 0, stream>>>(h2, h, csum2, csq2, g2, be2);

  // ---- per-graph mean readout (segment reduce over sorted n2g) ----
  readout_kernel<<<dim3(B, 8), 256, 0, stream>>>(h, gstart, qemb);

  // ---- MLP head (K-split partials + reduce w/ BN stats) ----
  fc1_partial_kernel<<<dim3(NROW/F1_ROWS, F1_NS), 256, 0, stream>>>(qemb, gstart, pg_emb, neigh, W_fc, part);
  reduce_stats_kernel<<<NROW/8, 256, 0, stream>>>(part, b_fc, G1, s1, q1, F1_NS);
  fc_mid_partial_kernel<<<dim3(NROW/FM_ROWS, FM_NS), 256, 0, stream>>>(G1, s1, q1, gb,  bb,  W_fc2, part);
  reduce_stats_kernel<<<NROW/8, 256, 0, stream>>>(part, b_fc2, G2, s2, q2, FM_NS);
  fc_mid_partial_kernel<<<dim3(NROW/FM_ROWS, FM_NS), 256, 0, stream>>>(G2, s2, q2, gb2, bb2, W_fc3, part);
  reduce_stats_kernel<<<NROW/8, 256, 0, stream>>>(part, b_fc3, G3, s3, q3, FM_NS);
  final_kernel<<<(NROW+3)/4, 256, 0, stream>>>(G3, s3, q3, gb3, bb3, W_fc4, b_fc4, out);
}

// Round 5
// 268.329 us; speedup vs baseline: 9.2689x; 1.0838x over previous
//
#include <hip/hip_runtime.h>
#include <hip/hip_bf16.h>
#include <math.h>

#define N_NODES 10000
#define N_EDGES 160000
#define D 512
#define DIN 20
#define B 64
#define KC 10
#define DH 256
#define NROW (B*KC)   // 640
#define BN_EPS 1e-5f

__device__ __forceinline__ void f4acc(float4& a, const float4 v){
  a.x += v.x; a.y += v.y; a.z += v.z; a.w += v.w;
}
__device__ __forceinline__ void mk_affine(const float4 s, const float4 q, const float4 g,
                                          const float4 b, float4& sc, float4& sh){
  const float invN = 1.0f/(float)N_NODES;
  float mu, var, rs;
  mu = s.x*invN; var = q.x*invN - mu*mu; rs = rsqrtf(var+BN_EPS); sc.x = rs*g.x; sh.x = b.x - mu*sc.x;
  mu = s.y*invN; var = q.y*invN - mu*mu; rs = rsqrtf(var+BN_EPS); sc.y = rs*g.y; sh.y = b.y - mu*sc.y;
  mu = s.z*invN; var = q.z*invN - mu*mu; rs = rsqrtf(var+BN_EPS); sc.z = rs*g.z; sh.z = b.z - mu*sc.z;
  mu = s.w*invN; var = q.w*invN - mu*mu; rs = rsqrtf(var+BN_EPS); sc.w = rs*g.w; sh.w = b.w - mu*sc.w;
}
__device__ __forceinline__ float4 aff_relu(const float4 v, const float4 sc, const float4 sh){
  float4 o;
  o.x = fmaxf(fmaf(v.x, sc.x, sh.x), 0.0f);
  o.y = fmaxf(fmaf(v.y, sc.y, sh.y), 0.0f);
  o.z = fmaxf(fmaf(v.z, sc.z, sh.z), 0.0f);
  o.w = fmaxf(fmaf(v.w, sc.w, sh.w), 0.0f);
  return o;
}

// ---------------- setup: zero scratch (parallel) + graph bounds (last block) ----------------
#define ZCOUNT 36352            // csum1,csq1,csum2,csq2 (2048) + s1..q3 (1536) + qemb (32768)
#define Z4 (ZCOUNT/4)           // 9088
#define D4 (N_NODES/4)          // 2500
#define SETUP_ZBLK ((Z4 + D4 + 255)/256)   // 46
__global__ void setup_kernel(const int* __restrict__ n2g, int* __restrict__ gstart,
                             float* __restrict__ zbuf, int* __restrict__ degi){
  if (blockIdx.x == SETUP_ZBLK){
    int g = threadIdx.x;
    if (g > B) return;
    int lo = 0, hi = N_NODES;
    while (lo < hi){ int mid = (lo+hi)>>1; if (n2g[mid] < g) lo = mid+1; else hi = mid; }
    gstart[g] = lo;
    return;
  }
  int i4 = blockIdx.x*256 + threadIdx.x;
  if (i4 < Z4){
    ((float4*)zbuf)[i4] = make_float4(0.f,0.f,0.f,0.f);
  } else {
    int j = i4 - Z4;
    if (j < D4) ((int4*)degi)[j] = make_int4(0,0,0,0);
  }
}

// ---------------- degree histogram (int) ----------------
__global__ void deg_kernel(const int* __restrict__ dst, int* __restrict__ degi, int E){
  int i = blockIdx.x*blockDim.x + threadIdx.x;
  if (i < E) atomicAdd(&degi[dst[i]], 1);
}

// ---------------- single-block scan over degrees ----------------
__global__ void scan_kernel(const int* __restrict__ degi, int* __restrict__ rowstart,
                            int* __restrict__ cursor){
  __shared__ int part[256];
  int t = threadIdx.x;
  const int PER = (N_NODES + 255)/256; // 40
  int base = t*PER;
  int s = 0;
  for (int i = 0; i < PER; ++i){
    int idx = base+i;
    if (idx < N_NODES) s += degi[idx];
  }
  part[t] = s;
  __syncthreads();
  for (int off = 1; off < 256; off <<= 1){
    int v = (t >= off) ? part[t-off] : 0;
    __syncthreads();
    part[t] += v;
    __syncthreads();
  }
  int run = (t > 0) ? part[t-1] : 0;
  for (int i = 0; i < PER; ++i){
    int idx = base+i;
    if (idx < N_NODES){
      rowstart[idx] = run; cursor[idx] = run; run += degi[idx];
    }
  }
  if (t == 255) rowstart[N_NODES] = run;
}

// ---------------- CSR fill: csr[pos] = src, bucketed by dst ----------------
__global__ void fill_kernel(const int* __restrict__ src, const int* __restrict__ dst,
                            int* __restrict__ cursor, int* __restrict__ csr, int E){
  int i = blockIdx.x*blockDim.x + threadIdx.x;
  if (i < E){
    int p = atomicAdd(&cursor[dst[i]], 1);
    csr[p] = src[i];
  }
}

// ---------------- h = x @ W_init + b_init  (W staged in LDS, 8 rows/block) ----------------
#define IM_ROWS 8
__global__ __launch_bounds__(256)
void init_mm_kernel(const float* __restrict__ x, const float* __restrict__ W,
                    const float* __restrict__ b, float* __restrict__ h){
  __shared__ float Ws[DIN][D];        // 40 KB
  __shared__ float xs[IM_ROWS][DIN];
  int t = threadIdx.x;
  int r0 = blockIdx.x*IM_ROWS;
  for (int i = t; i < DIN*D; i += 256) Ws[i >> 9][i & (D-1)] = W[i];
  for (int i = t; i < IM_ROWS*DIN; i += 256) xs[i/DIN][i%DIN] = x[(size_t)r0*DIN + i];
  __syncthreads();
  float b0 = b[t], b1 = b[t+256];
  for (int rr = 0; rr < IM_ROWS; ++rr){
    float a0 = b0, a1 = b1;
    #pragma unroll
    for (int k = 0; k < DIN; ++k){
      float xv = xs[rr][k];
      a0 += xv*Ws[k][t];
      a1 += xv*Ws[k][t+256];
    }
    h[(size_t)(r0+rr)*D + t]       = a0;
    h[(size_t)(r0+rr)*D + t + 256] = a1;
  }
}

// ---------------- GIN gather (optionally fusing relu(BN_prev(.)) on loads) ----------------
#define GWAVES 4
#define NPW 4
#define NWAVETOT (N_NODES/NPW)   // 2500
template<bool FUSED>
__global__ __launch_bounds__(256, 2)
void gin_gather_kernel(const float* __restrict__ h,
                       const int* __restrict__ rowstart,
                       const int* __restrict__ csr,
                       const float* __restrict__ pcsum, const float* __restrict__ pcsq,
                       const float* __restrict__ pgam, const float* __restrict__ pbet,
                       float* __restrict__ h2,
                       float* __restrict__ csum, float* __restrict__ csq){
  __shared__ float red[GWAVES][1024];
  int lane = threadIdx.x & 63;
  int wave = threadIdx.x >> 6;
  int wid  = blockIdx.x*GWAVES + wave;   // 0..2499
  const float4* h4 = (const float4*)h;
  float4 scA, shA, scB, shB;
  if (FUSED){
    mk_affine(((const float4*)pcsum)[lane],    ((const float4*)pcsq)[lane],
              ((const float4*)pgam)[lane],     ((const float4*)pbet)[lane],    scA, shA);
    mk_affine(((const float4*)pcsum)[lane+64], ((const float4*)pcsq)[lane+64],
              ((const float4*)pgam)[lane+64],  ((const float4*)pbet)[lane+64], scB, shB);
  }
  float4 sA = make_float4(0,0,0,0), sB = make_float4(0,0,0,0);
  float4 qA = make_float4(0,0,0,0), qB = make_float4(0,0,0,0);
  for (int nn = 0; nn < NPW; ++nn){
    int node = wid + nn*NWAVETOT;
    int start = rowstart[node], end = rowstart[node+1];
    float4 aA = make_float4(0,0,0,0), aB = make_float4(0,0,0,0);
    float4 bA = make_float4(0,0,0,0), bB = make_float4(0,0,0,0);
    for (int base = start; base < end; base += 64){
      int cnt = end - base; if (cnt > 64) cnt = 64;
      int myidx = (lane < cnt) ? csr[base+lane] : 0;
      int j = 0;
      for (; j+4 <= cnt; j += 4){
        int i0 = __shfl(myidx, j,   64);
        int i1 = __shfl(myidx, j+1, 64);
        int i2 = __shfl(myidx, j+2, 64);
        int i3 = __shfl(myidx, j+3, 64);
        const float4* r0 = h4 + (size_t)i0*(D/4);
        const float4* r1 = h4 + (size_t)i1*(D/4);
        const float4* r2 = h4 + (size_t)i2*(D/4);
        const float4* r3 = h4 + (size_t)i3*(D/4);
        float4 va0 = r0[lane], vb0 = r0[lane+64];
        float4 va1 = r1[lane], vb1 = r1[lane+64];
        float4 va2 = r2[lane], vb2 = r2[lane+64];
        float4 va3 = r3[lane], vb3 = r3[lane+64];
        if (FUSED){
          va0 = aff_relu(va0, scA, shA); vb0 = aff_relu(vb0, scB, shB);
          va1 = aff_relu(va1, scA, shA); vb1 = aff_relu(vb1, scB, shB);
          va2 = aff_relu(va2, scA, shA); vb2 = aff_relu(vb2, scB, shB);
          va3 = aff_relu(va3, scA, shA); vb3 = aff_relu(vb3, scB, shB);
        }
        f4acc(aA, va0); f4acc(bA, vb0);
        f4acc(aB, va1); f4acc(bB, vb1);
        f4acc(aA, va2); f4acc(bA, vb2);
        f4acc(aB, va3); f4acc(bB, vb3);
      }
      for (; j < cnt; ++j){
        int i0 = __shfl(myidx, j, 64);
        const float4* r0 = h4 + (size_t)i0*(D/4);
        float4 va = r0[lane], vb = r0[lane+64];
        if (FUSED){ va = aff_relu(va, scA, shA); vb = aff_relu(vb, scB, shB); }
        f4acc(aA, va); f4acc(bA, vb);
      }
    }
    float inv = 1.0f/fmaxf((float)(end-start), 1.0f);
    float4 hva = h4[(size_t)node*(D/4) + lane];
    float4 hvb = h4[(size_t)node*(D/4) + 64 + lane];
    if (FUSED){ hva = aff_relu(hva, scA, shA); hvb = aff_relu(hvb, scB, shB); }
    float4 oA, oB;
    oA.x = hva.x + (aA.x+aB.x)*inv;  oA.y = hva.y + (aA.y+aB.y)*inv;
    oA.z = hva.z + (aA.z+aB.z)*inv;  oA.w = hva.w + (aA.w+aB.w)*inv;
    oB.x = hvb.x + (bA.x+bB.x)*inv;  oB.y = hvb.y + (bA.y+bB.y)*inv;
    oB.z = hvb.z + (bA.z+bB.z)*inv;  oB.w = hvb.w + (bA.w+bB.w)*inv;
    ((float4*)(h2 + (size_t)node*D))[lane]      = oA;
    ((float4*)(h2 + (size_t)node*D))[lane + 64] = oB;
    f4acc(sA, oA); f4acc(sB, oB);
    qA.x += oA.x*oA.x; qA.y += oA.y*oA.y; qA.z += oA.z*oA.z; qA.w += oA.w*oA.w;
    qB.x += oB.x*oB.x; qB.y += oB.y*oB.y; qB.z += oB.z*oB.z; qB.w += oB.w*oB.w;
  }
  float* my = red[wave];
  int c = 4*lane;
  my[c+0]=sA.x; my[c+1]=sA.y; my[c+2]=sA.z; my[c+3]=sA.w;
  my[256+c+0]=sB.x; my[256+c+1]=sB.y; my[256+c+2]=sB.z; my[256+c+3]=sB.w;
  my[512+c+0]=qA.x; my[512+c+1]=qA.y; my[512+c+2]=qA.z; my[512+c+3]=qA.w;
  my[768+c+0]=qB.x; my[768+c+1]=qB.y; my[768+c+2]=qB.z; my[768+c+3]=qB.w;
  __syncthreads();
  for (int e = threadIdx.x; e < 1024; e += 256){
    float v = red[0][e] + red[1][e] + red[2][e] + red[3][e];
    if (e < 512) atomicAdd(&csum[e], v);
    else         atomicAdd(&csq[e-512], v);
  }
}

// ---------------- per-graph mean readout with fused relu(BN2(.)) ----------------
__global__ void readout_kernel(const float* __restrict__ h,
                               const float* __restrict__ csum, const float* __restrict__ csq,
                               const float* __restrict__ gam, const float* __restrict__ bet,
                               const int* __restrict__ gstart, float* __restrict__ qemb){
  int g = blockIdx.x, chunk = blockIdx.y;
  int t = threadIdx.x;
  const float invN = 1.0f/(float)N_NODES;
  float mu0 = csum[t]*invN;
  float rs0 = rsqrtf(csq[t]*invN - mu0*mu0 + BN_EPS);
  float sc0 = rs0*gam[t], sh0 = bet[t] - mu0*sc0;
  float mu1 = csum[t+256]*invN;
  float rs1 = rsqrtf(csq[t+256]*invN - mu1*mu1 + BN_EPS);
  float sc1 = rs1*gam[t+256], sh1 = bet[t+256] - mu1*sc1;
  int s = gstart[g], e = gstart[g+1];
  int rows = e - s;
  int per = (rows + 7)/8;
  int r0 = s + chunk*per;
  int r1 = r0 + per; if (r1 > e) r1 = e;
  if (r0 >= r1) return;
  float a0=0.f, b0=0.f;
  for (int r = r0; r < r1; ++r){
    a0 += fmaxf(fmaf(h[(size_t)r*D + t],       sc0, sh0), 0.0f);
    b0 += fmaxf(fmaf(h[(size_t)r*D + t + 256], sc1, sh1), 0.0f);
  }
  atomicAdd(&qemb[(size_t)g*D + t],       a0);
  atomicAdd(&qemb[(size_t)g*D + t + 256], b0);
}

// ---------------- FC1 partials: [640,1536]@[1536,256], K split 6x256 ----------------
#define F1_ROWS 8
#define F1_KS 256
#define F1_NS 6
__global__ __launch_bounds__(256)
void fc1_partial_kernel(const float* __restrict__ qemb, const int* __restrict__ gstart,
                        const float* __restrict__ pg, const float* __restrict__ neigh,
                        const float* __restrict__ W, float* __restrict__ part){
  __shared__ float brow[F1_ROWS][F1_KS];
  int t = threadIdx.x;
  int r0 = blockIdx.x*F1_ROWS;
  int k0 = blockIdx.y*F1_KS;
  for (int rr=0; rr<F1_ROWS; ++rr){
    int r = r0+rr;
    int g = r/KC, k = r - g*KC;
    int j = k0 + t;
    float v;
    if (j < D){
      float invc = 1.0f/fmaxf((float)(gstart[g+1]-gstart[g]), 1.0f);
      v = qemb[(size_t)g*D + j]*invc;
    } else if (j < 2*D){
      v = pg[(size_t)g*D + (j-D)];
    } else {
      v = neigh[((size_t)g*KC + k)*D + (j-2*D)];
    }
    brow[rr][t] = v;
  }
  __syncthreads();
  float acc[F1_ROWS] = {0.f,0.f,0.f,0.f,0.f,0.f,0.f,0.f};
  #pragma unroll 4
  for (int kk=0; kk<F1_KS; ++kk){
    float w = W[(size_t)(k0+kk)*DH + t];
    #pragma unroll
    for (int rr=0; rr<F1_ROWS; ++rr) acc[rr] += brow[rr][kk]*w;
  }
  for (int rr=0; rr<F1_ROWS; ++rr)
    part[((size_t)blockIdx.y*NROW + r0+rr)*DH + t] = acc[rr];
}

// ---------------- reduce partials + bias, write out, accumulate BN stats ----------------
__global__ __launch_bounds__(256)
void reduce_stats_kernel(const float* __restrict__ part, const float* __restrict__ bias,
                         float* __restrict__ out, float* __restrict__ s, float* __restrict__ q,
                         int nslice){
  int t = threadIdx.x;            // col
  int r0 = blockIdx.x*8;
  float bval = bias[t];
  float ls = 0.f, lq = 0.f;
  for (int rr = 0; rr < 8; ++rr){
    int r = r0+rr;
    float acc = bval;
    for (int sl = 0; sl < nslice; ++sl) acc += part[((size_t)sl*NROW + r)*DH + t];
    out[(size_t)r*DH + t] = acc;
    ls += acc; lq += acc*acc;
  }
  atomicAdd(&s[t], ls); atomicAdd(&q[t], lq);
}

// ---------------- FC mid partials: BN(prev)+relu staged, K split 2x128 ----------------
#define FM_ROWS 4
#define FM_KS 128
#define FM_NS 2
__global__ __launch_bounds__(256)
void fc_mid_partial_kernel(const float* __restrict__ in, const float* __restrict__ ps,
                           const float* __restrict__ pq, const float* __restrict__ gamma,
                           const float* __restrict__ beta, const float* __restrict__ W,
                           float* __restrict__ part){
  __shared__ float row[FM_ROWS][FM_KS];
  int t = threadIdx.x;
  int r0 = blockIdx.x*FM_ROWS;
  int k0 = blockIdx.y*FM_KS;
  const float invM = 1.0f/(float)NROW;
  #pragma unroll
  for (int i = 0; i < 2; ++i){
    int idx = t + i*256;          // 0..511
    int rr = idx >> 7, kk = idx & 127;
    int c = k0 + kk;
    float mu = ps[c]*invM;
    float var = pq[c]*invM - mu*mu;
    float rs = rsqrtf(var + BN_EPS);
    float v = in[(size_t)(r0+rr)*DH + c];
    row[rr][kk] = fmaxf((v-mu)*rs*gamma[c] + beta[c], 0.0f);
  }
  __syncthreads();
  float acc[FM_ROWS] = {0.f,0.f,0.f,0.f};
  #pragma unroll 4
  for (int kk=0; kk<FM_KS; ++kk){
    float w = W[(size_t)(k0+kk)*DH + t];
    #pragma unroll
    for (int rr=0; rr<FM_ROWS; ++rr) acc[rr] += row[rr][kk]*w;
  }
  for (int rr=0; rr<FM_ROWS; ++rr)
    part[((size_t)blockIdx.y*NROW + r0+rr)*DH + t] = acc[rr];
}

// ---------------- final: BN3+relu, dot W_fc4, sigmoid ----------------
__global__ void final_kernel(const float* __restrict__ G3, const float* __restrict__ ps,
                             const float* __restrict__ pq, const float* __restrict__ gamma,
                             const float* __restrict__ beta,
                             const float* __restrict__ w4, const float* __restrict__ b4,
                             float* __restrict__ out){
  int wave = threadIdx.x>>6, lane = threadIdx.x&63;
  int r = blockIdx.x*4 + wave;
  if (r >= NROW) return;
  const float invM = 1.0f/(float)NROW;
  float sum = 0.f;
  #pragma unroll
  for (int j=0;j<4;++j){
    int c = lane + 64*j;
    float mu = ps[c]*invM;
    float var = pq[c]*invM - mu*mu;
    float rs = rsqrtf(var+BN_EPS);
    float v = G3[(size_t)r*DH + c];
    v = fmaxf((v-mu)*rs*gamma[c]+beta[c], 0.0f);
    sum += v*w4[c];
  }
  #pragma unroll
  for (int off=32; off>0; off>>=1) sum += __shfl_down(sum, off, 64);
  if (lane==0){
    float z = sum + b4[0];
    out[r] = 1.0f/(1.0f + expf(-z));
  }
}

extern "C" void kernel_launch(void* const* d_in, const int* in_sizes, int n_in,
                              void* d_out, int out_size, void* d_ws, size_t ws_size,
                              hipStream_t stream) {
  const float* x        = (const float*)d_in[0];
  const float* pg_emb   = (const float*)d_in[1];
  const float* neigh    = (const float*)d_in[2];
  const float* W_init   = (const float*)d_in[3];
  const float* b_init   = (const float*)d_in[4];
  const float* g1       = (const float*)d_in[5];
  const float* be1      = (const float*)d_in[6];
  const float* g2       = (const float*)d_in[7];
  const float* be2      = (const float*)d_in[8];
  const float* W_fc     = (const float*)d_in[9];
  const float* b_fc     = (const float*)d_in[10];
  const float* W_fc2    = (const float*)d_in[11];
  const float* b_fc2    = (const float*)d_in[12];
  const float* W_fc3    = (const float*)d_in[13];
  const float* b_fc3    = (const float*)d_in[14];
  const float* W_fc4    = (const float*)d_in[15];
  const float* b_fc4    = (const float*)d_in[16];
  const float* gb       = (const float*)d_in[17];
  const float* bb       = (const float*)d_in[18];
  const float* gb2      = (const float*)d_in[19];
  const float* bb2      = (const float*)d_in[20];
  const float* gb3      = (const float*)d_in[21];
  const float* bb3      = (const float*)d_in[22];
  const int*   esrc     = (const int*)d_in[23];
  const int*   edst     = (const int*)d_in[24];
  const int*   n2g      = (const int*)d_in[25];
  float* out = (float*)d_out;

  float* ws = (float*)d_ws;
  size_t off = 0;
  float* h    = ws + off; off += (size_t)N_NODES*D;
  float* hB   = ws + off; off += (size_t)N_NODES*D;   // h2_1; reused as MLP partials
  // ---- contiguous region zeroed by setup_kernel (ZCOUNT floats) ----
  float* zbase = ws + off;
  float* csum1 = ws + off; off += 512;
  float* csq1  = ws + off; off += 512;
  float* csum2 = ws + off; off += 512;
  float* csq2  = ws + off; off += 512;
  float* s1    = ws + off; off += 256;
  float* q1    = ws + off; off += 256;
  float* s2    = ws + off; off += 256;
  float* q2    = ws + off; off += 256;
  float* s3    = ws + off; off += 256;
  float* q3    = ws + off; off += 256;
  float* qemb  = ws + off; off += (size_t)B*D;        // 32768
  // ---- end zero region (36352 floats == ZCOUNT) ----
  float* G1   = ws + off; off += (size_t)NROW*DH;
  float* G2   = ws + off; off += (size_t)NROW*DH;
  float* G3   = ws + off; off += (size_t)NROW*DH;
  int* degi     = (int*)(ws + off); off += N_NODES;   // 16B-aligned (offset mult of 4)
  int* rowstart = (int*)(ws + off); off += N_NODES + 1;
  int* cursor   = (int*)(ws + off); off += N_NODES;
  int* csr      = (int*)(ws + off); off += N_EDGES;
  int* gstart   = (int*)(ws + off); off += B + 1;
  float* part = hB;  // MLP head partials (hB free after gather2)
  (void)zbase;

  // ---- setup: zero scratch + graph bounds; then CSR build ----
  setup_kernel<<<SETUP_ZBLK+1, 256, 0, stream>>>(n2g, gstart, csum1, degi);
  deg_kernel<<<(N_EDGES+255)/256, 256, 0, stream>>>(edst, degi, N_EDGES);
  scan_kernel<<<1, 256, 0, stream>>>(degi, rowstart, cursor);
  fill_kernel<<<(N_EDGES+255)/256, 256, 0, stream>>>(esrc, edst, cursor, csr, N_EDGES);

  // ---- initial projection ----
  init_mm_kernel<<<N_NODES/IM_ROWS, 256, 0, stream>>>(x, W_init, b_init, h);

  // ---- GIN layer 1: h -> hB (raw pre-BN), stats into csum1/csq1 ----
  gin_gather_kernel<false><<<NWAVETOT/GWAVES, 256, 0, stream>>>(
      h, rowstart, csr, nullptr, nullptr, nullptr, nullptr, hB, csum1, csq1);
  // ---- GIN layer 2: reads relu(BN1(hB)) on the fly -> h (raw pre-BN), stats csum2/csq2 ----
  gin_gather_kernel<true><<<NWAVETOT/GWAVES, 256, 0, stream>>>(
      hB, rowstart, csr, csum1, csq1, g1, be1, h, csum2, csq2);

  // ---- per-graph mean readout of relu(BN2(h)) ----
  readout_kernel<<<dim3(B, 8), 256, 0, stream>>>(h, csum2, csq2, g2, be2, gstart, qemb);

  // ---- MLP head (K-split partials + reduce w/ BN stats) ----
  fc1_partial_kernel<<<dim3(NROW/F1_ROWS, F1_NS), 256, 0, stream>>>(qemb, gstart, pg_emb, neigh, W_fc, part);
  reduce_stats_kernel<<<NROW/8, 256, 0, stream>>>(part, b_fc, G1, s1, q1, F1_NS);
  fc_mid_partial_kernel<<<dim3(NROW/FM_ROWS, FM_NS), 256, 0, stream>>>(G1, s1, q1, gb,  bb,  W_fc2, part);
  reduce_stats_kernel<<<NROW/8, 256, 0, stream>>>(part, b_fc2, G2, s2, q2, FM_NS);
  fc_mid_partial_kernel<<<dim3(NROW/FM_ROWS, FM_NS), 256, 0, stream>>>(G2, s2, q2, gb2, bb2, W_fc3, part);
  reduce_stats_kernel<<<NROW/8, 256, 0, stream>>>(part, b_fc3, G3, s3, q3, FM_NS);
  final_kernel<<<(NROW+3)/4, 256, 0, stream>>>(G3, s3, q3, gb3, bb3, W_fc4, b_fc4, out);
}

// Round 6
// 219.798 us; speedup vs baseline: 11.3154x; 1.2208x over previous
//
#include <hip/hip_runtime.h>
#include <hip/hip_bf16.h>
#include <math.h>

#define N_NODES 10000
#define N_EDGES 160000
#define D 512
#define DIN 20
#define B 64
#define KC 10
#define DH 256
#define NROW (B*KC)   // 640
#define BN_EPS 1e-5f

__device__ __forceinline__ void f4acc(float4& a, const float4 v){
  a.x += v.x; a.y += v.y; a.z += v.z; a.w += v.w;
}
__device__ __forceinline__ void mk_affine(const float4 s, const float4 q, const float4 g,
                                          const float4 b, float4& sc, float4& sh){
  const float invN = 1.0f/(float)N_NODES;
  float mu, var, rs;
  mu = s.x*invN; var = q.x*invN - mu*mu; rs = rsqrtf(var+BN_EPS); sc.x = rs*g.x; sh.x = b.x - mu*sc.x;
  mu = s.y*invN; var = q.y*invN - mu*mu; rs = rsqrtf(var+BN_EPS); sc.y = rs*g.y; sh.y = b.y - mu*sc.y;
  mu = s.z*invN; var = q.z*invN - mu*mu; rs = rsqrtf(var+BN_EPS); sc.z = rs*g.z; sh.z = b.z - mu*sc.z;
  mu = s.w*invN; var = q.w*invN - mu*mu; rs = rsqrtf(var+BN_EPS); sc.w = rs*g.w; sh.w = b.w - mu*sc.w;
}
__device__ __forceinline__ float4 aff_relu(const float4 v, const float4 sc, const float4 sh){
  float4 o;
  o.x = fmaxf(fmaf(v.x, sc.x, sh.x), 0.0f);
  o.y = fmaxf(fmaf(v.y, sc.y, sh.y), 0.0f);
  o.z = fmaxf(fmaf(v.z, sc.z, sh.z), 0.0f);
  o.w = fmaxf(fmaf(v.w, sc.w, sh.w), 0.0f);
  return o;
}
// unpack 8 bf16 (uint4) -> 2 float4 (elem order matches memory order)
__device__ __forceinline__ void bf_unpack(const uint4 u, float4& lo, float4& hi){
  lo.x = __uint_as_float(u.x << 16); lo.y = __uint_as_float(u.x & 0xffff0000u);
  lo.z = __uint_as_float(u.y << 16); lo.w = __uint_as_float(u.y & 0xffff0000u);
  hi.x = __uint_as_float(u.z << 16); hi.y = __uint_as_float(u.z & 0xffff0000u);
  hi.z = __uint_as_float(u.w << 16); hi.w = __uint_as_float(u.w & 0xffff0000u);
}
__device__ __forceinline__ unsigned bf_pack2(float a, float b){ // RNE
  unsigned ua = __float_as_uint(a); ua = (ua + 0x7fffu + ((ua>>16)&1u)) >> 16;
  unsigned ub = __float_as_uint(b); ub = (ub + 0x7fffu + ((ub>>16)&1u)) & 0xffff0000u;
  return (ua & 0xffffu) | ub;
}
__device__ __forceinline__ unsigned short bf_pack1(float a){
  unsigned ua = __float_as_uint(a); return (unsigned short)((ua + 0x7fffu + ((ua>>16)&1u)) >> 16);
}

// ---------------- setup: zero scratch (parallel) + graph bounds (last block) ----------------
#define ZCOUNT 36352            // csum1,csq1,csum2,csq2 (2048) + s1..q3 (1536) + qemb (32768)
#define Z4 (ZCOUNT/4)           // 9088
#define D4 (N_NODES/4)          // 2500
#define SETUP_ZBLK ((Z4 + D4 + 255)/256)   // 46
__global__ void setup_kernel(const int* __restrict__ n2g, int* __restrict__ gstart,
                             float* __restrict__ zbuf, int* __restrict__ degi){
  if (blockIdx.x == SETUP_ZBLK){
    int g = threadIdx.x;
    if (g > B) return;
    int lo = 0, hi = N_NODES;
    while (lo < hi){ int mid = (lo+hi)>>1; if (n2g[mid] < g) lo = mid+1; else hi = mid; }
    gstart[g] = lo;
    return;
  }
  int i4 = blockIdx.x*256 + threadIdx.x;
  if (i4 < Z4){
    ((float4*)zbuf)[i4] = make_float4(0.f,0.f,0.f,0.f);
  } else {
    int j = i4 - Z4;
    if (j < D4) ((int4*)degi)[j] = make_int4(0,0,0,0);
  }
}

// ---------------- degree histogram (int) ----------------
__global__ void deg_kernel(const int* __restrict__ dst, int* __restrict__ degi, int E){
  int i = blockIdx.x*blockDim.x + threadIdx.x;
  if (i < E) atomicAdd(&degi[dst[i]], 1);
}

// ---------------- single-block scan over degrees ----------------
__global__ void scan_kernel(const int* __restrict__ degi, int* __restrict__ rowstart,
                            int* __restrict__ cursor){
  __shared__ int part[256];
  int t = threadIdx.x;
  const int PER = (N_NODES + 255)/256; // 40
  int base = t*PER;
  int s = 0;
  for (int i = 0; i < PER; ++i){
    int idx = base+i;
    if (idx < N_NODES) s += degi[idx];
  }
  part[t] = s;
  __syncthreads();
  for (int off = 1; off < 256; off <<= 1){
    int v = (t >= off) ? part[t-off] : 0;
    __syncthreads();
    part[t] += v;
    __syncthreads();
  }
  int run = (t > 0) ? part[t-1] : 0;
  for (int i = 0; i < PER; ++i){
    int idx = base+i;
    if (idx < N_NODES){
      rowstart[idx] = run; cursor[idx] = run; run += degi[idx];
    }
  }
  if (t == 255) rowstart[N_NODES] = run;
}

// ---------------- CSR fill: csr[pos] = src, bucketed by dst ----------------
__global__ void fill_kernel(const int* __restrict__ src, const int* __restrict__ dst,
                            int* __restrict__ cursor, int* __restrict__ csr, int E){
  int i = blockIdx.x*blockDim.x + threadIdx.x;
  if (i < E){
    int p = atomicAdd(&cursor[dst[i]], 1);
    csr[p] = src[i];
  }
}

// ---------------- h(bf16) = x @ W_init + b_init  (W staged in LDS, 8 rows/block) ----------------
#define IM_ROWS 8
__global__ __launch_bounds__(256)
void init_mm_kernel(const float* __restrict__ x, const float* __restrict__ W,
                    const float* __restrict__ b, unsigned short* __restrict__ hb){
  __shared__ float Ws[DIN][D];        // 40 KB
  __shared__ float xs[IM_ROWS][DIN];
  int t = threadIdx.x;
  int r0 = blockIdx.x*IM_ROWS;
  for (int i = t; i < DIN*D; i += 256) Ws[i >> 9][i & (D-1)] = W[i];
  for (int i = t; i < IM_ROWS*DIN; i += 256) xs[i/DIN][i%DIN] = x[(size_t)r0*DIN + i];
  __syncthreads();
  float b0 = b[t], b1 = b[t+256];
  for (int rr = 0; rr < IM_ROWS; ++rr){
    float a0 = b0, a1 = b1;
    #pragma unroll
    for (int k = 0; k < DIN; ++k){
      float xv = xs[rr][k];
      a0 += xv*Ws[k][t];
      a1 += xv*Ws[k][t+256];
    }
    hb[(size_t)(r0+rr)*D + t]       = bf_pack1(a0);
    hb[(size_t)(r0+rr)*D + t + 256] = bf_pack1(a1);
  }
}

// ---------------- GIN gather over bf16 features (optional fused relu(BN_prev)) ----------------
#define GWAVES 4
#define NPW 4
#define NWAVETOT (N_NODES/NPW)   // 2500
template<bool FUSED>
__global__ __launch_bounds__(256, 2)
void gin_gather_kernel(const unsigned short* __restrict__ hb,   // raw bf16 features in
                       const int* __restrict__ rowstart,
                       const int* __restrict__ csr,
                       const float* __restrict__ pcsum, const float* __restrict__ pcsq,
                       const float* __restrict__ pgam, const float* __restrict__ pbet,
                       unsigned short* __restrict__ h2b,        // raw bf16 features out
                       float* __restrict__ csum, float* __restrict__ csq){
  __shared__ float red[GWAVES][1024];
  int lane = threadIdx.x & 63;
  int wave = threadIdx.x >> 6;
  int wid  = blockIdx.x*GWAVES + wave;   // 0..2499
  const uint4* hb4 = (const uint4*)hb;   // row stride = 64 uint4
  float4 scA, shA, scB, shB;
  if (FUSED){
    mk_affine(((const float4*)pcsum)[2*lane],   ((const float4*)pcsq)[2*lane],
              ((const float4*)pgam)[2*lane],    ((const float4*)pbet)[2*lane],   scA, shA);
    mk_affine(((const float4*)pcsum)[2*lane+1], ((const float4*)pcsq)[2*lane+1],
              ((const float4*)pgam)[2*lane+1],  ((const float4*)pbet)[2*lane+1], scB, shB);
  }
  float4 sLo = make_float4(0,0,0,0), sHi = make_float4(0,0,0,0);
  float4 qLo = make_float4(0,0,0,0), qHi = make_float4(0,0,0,0);
  for (int nn = 0; nn < NPW; ++nn){
    int node = wid + nn*NWAVETOT;
    int start = rowstart[node], end = rowstart[node+1];
    float4 aLo = make_float4(0,0,0,0), aHi = make_float4(0,0,0,0);
    float4 bLo = make_float4(0,0,0,0), bHi = make_float4(0,0,0,0);
    for (int base = start; base < end; base += 64){
      int cnt = end - base; if (cnt > 64) cnt = 64;
      int myidx = (lane < cnt) ? csr[base+lane] : 0;
      int j = 0;
      for (; j+8 <= cnt; j += 8){
        uint4 u[8];
        #pragma unroll
        for (int k = 0; k < 8; ++k){
          int idx = __shfl(myidx, j+k, 64);
          u[k] = hb4[(size_t)idx*64 + lane];
        }
        #pragma unroll
        for (int k = 0; k < 8; ++k){
          float4 lo, hi; bf_unpack(u[k], lo, hi);
          if (FUSED){ lo = aff_relu(lo, scA, shA); hi = aff_relu(hi, scB, shB); }
          if (k & 1){ f4acc(bLo, lo); f4acc(bHi, hi); }
          else      { f4acc(aLo, lo); f4acc(aHi, hi); }
        }
      }
      for (; j < cnt; ++j){
        int idx = __shfl(myidx, j, 64);
        uint4 u0 = hb4[(size_t)idx*64 + lane];
        float4 lo, hi; bf_unpack(u0, lo, hi);
        if (FUSED){ lo = aff_relu(lo, scA, shA); hi = aff_relu(hi, scB, shB); }
        f4acc(aLo, lo); f4acc(aHi, hi);
      }
    }
    float inv = 1.0f/fmaxf((float)(end-start), 1.0f);
    uint4 us = hb4[(size_t)node*64 + lane];
    float4 hLo, hHi; bf_unpack(us, hLo, hHi);
    if (FUSED){ hLo = aff_relu(hLo, scA, shA); hHi = aff_relu(hHi, scB, shB); }
    float4 oLo, oHi;
    oLo.x = hLo.x + (aLo.x+bLo.x)*inv;  oLo.y = hLo.y + (aLo.y+bLo.y)*inv;
    oLo.z = hLo.z + (aLo.z+bLo.z)*inv;  oLo.w = hLo.w + (aLo.w+bLo.w)*inv;
    oHi.x = hHi.x + (aHi.x+bHi.x)*inv;  oHi.y = hHi.y + (aHi.y+bHi.y)*inv;
    oHi.z = hHi.z + (aHi.z+bHi.z)*inv;  oHi.w = hHi.w + (aHi.w+bHi.w)*inv;
    uint4 ou;
    ou.x = bf_pack2(oLo.x, oLo.y); ou.y = bf_pack2(oLo.z, oLo.w);
    ou.z = bf_pack2(oHi.x, oHi.y); ou.w = bf_pack2(oHi.z, oHi.w);
    ((uint4*)h2b)[(size_t)node*64 + lane] = ou;
    f4acc(sLo, oLo); f4acc(sHi, oHi);
    qLo.x += oLo.x*oLo.x; qLo.y += oLo.y*oLo.y; qLo.z += oLo.z*oLo.z; qLo.w += oLo.w*oLo.w;
    qHi.x += oHi.x*oHi.x; qHi.y += oHi.y*oHi.y; qHi.z += oHi.z*oHi.z; qHi.w += oHi.w*oHi.w;
  }
  float* my = red[wave];
  int c = 8*lane;
  *((float4*)&my[c])      = sLo;  *((float4*)&my[c+4])     = sHi;
  *((float4*)&my[512+c])  = qLo;  *((float4*)&my[512+c+4]) = qHi;
  __syncthreads();
  for (int e = threadIdx.x; e < 1024; e += 256){
    float v = red[0][e] + red[1][e] + red[2][e] + red[3][e];
    if (e < 512) atomicAdd(&csum[e], v);
    else         atomicAdd(&csq[e-512], v);
  }
}

// ---------------- per-graph mean readout of relu(BN2(bf16 h)) ----------------
__global__ void readout_kernel(const unsigned short* __restrict__ hb,
                               const float* __restrict__ csum, const float* __restrict__ csq,
                               const float* __restrict__ gam, const float* __restrict__ bet,
                               const int* __restrict__ gstart, float* __restrict__ qemb){
  __shared__ float red[4][512];
  int g = blockIdx.x, chunk = blockIdx.y;
  int lane = threadIdx.x & 63, wave = threadIdx.x >> 6;
  const uint4* hb4 = (const uint4*)hb;
  float4 scA, shA, scB, shB;
  mk_affine(((const float4*)csum)[2*lane],   ((const float4*)csq)[2*lane],
            ((const float4*)gam)[2*lane],    ((const float4*)bet)[2*lane],   scA, shA);
  mk_affine(((const float4*)csum)[2*lane+1], ((const float4*)csq)[2*lane+1],
            ((const float4*)gam)[2*lane+1],  ((const float4*)bet)[2*lane+1], scB, shB);
  int s = gstart[g], e = gstart[g+1];
  int rows = e - s;
  int per = (rows + 7)/8;
  int r0 = s + chunk*per;
  int r1 = r0 + per; if (r1 > e) r1 = e;
  float4 aLo = make_float4(0,0,0,0), aHi = make_float4(0,0,0,0);
  for (int r = r0 + wave; r < r1; r += 4){
    uint4 u = hb4[(size_t)r*64 + lane];
    float4 lo, hi; bf_unpack(u, lo, hi);
    lo = aff_relu(lo, scA, shA); hi = aff_relu(hi, scB, shB);
    f4acc(aLo, lo); f4acc(aHi, hi);
  }
  int c = 8*lane;
  *((float4*)&red[wave][c])   = aLo;
  *((float4*)&red[wave][c+4]) = aHi;
  __syncthreads();
  for (int e2 = threadIdx.x; e2 < 512; e2 += 256){
    float v = red[0][e2] + red[1][e2] + red[2][e2] + red[3][e2];
    atomicAdd(&qemb[(size_t)g*D + e2], v);
  }
}

// ---------------- FC1 partials: [640,1536]@[1536,256], K split 6x256 ----------------
#define F1_ROWS 8
#define F1_KS 256
#define F1_NS 6
__global__ __launch_bounds__(256)
void fc1_partial_kernel(const float* __restrict__ qemb, const int* __restrict__ gstart,
                        const float* __restrict__ pg, const float* __restrict__ neigh,
                        const float* __restrict__ W, float* __restrict__ part){
  __shared__ float brow[F1_ROWS][F1_KS];
  int t = threadIdx.x;
  int r0 = blockIdx.x*F1_ROWS;
  int k0 = blockIdx.y*F1_KS;
  for (int rr=0; rr<F1_ROWS; ++rr){
    int r = r0+rr;
    int g = r/KC, k = r - g*KC;
    int j = k0 + t;
    float v;
    if (j < D){
      float invc = 1.0f/fmaxf((float)(gstart[g+1]-gstart[g]), 1.0f);
      v = qemb[(size_t)g*D + j]*invc;
    } else if (j < 2*D){
      v = pg[(size_t)g*D + (j-D)];
    } else {
      v = neigh[((size_t)g*KC + k)*D + (j-2*D)];
    }
    brow[rr][t] = v;
  }
  __syncthreads();
  float acc[F1_ROWS] = {0.f,0.f,0.f,0.f,0.f,0.f,0.f,0.f};
  #pragma unroll 4
  for (int kk=0; kk<F1_KS; ++kk){
    float w = W[(size_t)(k0+kk)*DH + t];
    #pragma unroll
    for (int rr=0; rr<F1_ROWS; ++rr) acc[rr] += brow[rr][kk]*w;
  }
  for (int rr=0; rr<F1_ROWS; ++rr)
    part[((size_t)blockIdx.y*NROW + r0+rr)*DH + t] = acc[rr];
}

// ---------------- reduce partials + bias, write out, accumulate BN stats ----------------
__global__ __launch_bounds__(256)
void reduce_stats_kernel(const float* __restrict__ part, const float* __restrict__ bias,
                         float* __restrict__ out, float* __restrict__ s, float* __restrict__ q,
                         int nslice){
  int t = threadIdx.x;            // col
  int r0 = blockIdx.x*8;
  float bval = bias[t];
  float ls = 0.f, lq = 0.f;
  for (int rr = 0; rr < 8; ++rr){
    int r = r0+rr;
    float acc = bval;
    for (int sl = 0; sl < nslice; ++sl) acc += part[((size_t)sl*NROW + r)*DH + t];
    out[(size_t)r*DH + t] = acc;
    ls += acc; lq += acc*acc;
  }
  atomicAdd(&s[t], ls); atomicAdd(&q[t], lq);
}

// ---------------- FC mid partials: BN(prev)+relu staged, K split 2x128 ----------------
#define FM_ROWS 4
#define FM_KS 128
#define FM_NS 2
__global__ __launch_bounds__(256)
void fc_mid_partial_kernel(const float* __restrict__ in, const float* __restrict__ ps,
                           const float* __restrict__ pq, const float* __restrict__ gamma,
                           const float* __restrict__ beta, const float* __restrict__ W,
                           float* __restrict__ part){
  __shared__ float row[FM_ROWS][FM_KS];
  int t = threadIdx.x;
  int r0 = blockIdx.x*FM_ROWS;
  int k0 = blockIdx.y*FM_KS;
  const float invM = 1.0f/(float)NROW;
  #pragma unroll
  for (int i = 0; i < 2; ++i){
    int idx = t + i*256;          // 0..511
    int rr = idx >> 7, kk = idx & 127;
    int c = k0 + kk;
    float mu = ps[c]*invM;
    float var = pq[c]*invM - mu*mu;
    float rs = rsqrtf(var + BN_EPS);
    float v = in[(size_t)(r0+rr)*DH + c];
    row[rr][kk] = fmaxf((v-mu)*rs*gamma[c] + beta[c], 0.0f);
  }
  __syncthreads();
  float acc[FM_ROWS] = {0.f,0.f,0.f,0.f};
  #pragma unroll 4
  for (int kk=0; kk<FM_KS; ++kk){
    float w = W[(size_t)(k0+kk)*DH + t];
    #pragma unroll
    for (int rr=0; rr<FM_ROWS; ++rr) acc[rr] += row[rr][kk]*w;
  }
  for (int rr=0; rr<FM_ROWS; ++rr)
    part[((size_t)blockIdx.y*NROW + r0+rr)*DH + t] = acc[rr];
}

// ---------------- final: BN3+relu, dot W_fc4, sigmoid ----------------
__global__ void final_kernel(const float* __restrict__ G3, const float* __restrict__ ps,
                             const float* __restrict__ pq, const float* __restrict__ gamma,
                             const float* __restrict__ beta,
                             const float* __restrict__ w4, const float* __restrict__ b4,
                             float* __restrict__ out){
  int wave = threadIdx.x>>6, lane = threadIdx.x&63;
  int r = blockIdx.x*4 + wave;
  if (r >= NROW) return;
  const float invM = 1.0f/(float)NROW;
  float sum = 0.f;
  #pragma unroll
  for (int j=0;j<4;++j){
    int c = lane + 64*j;
    float mu = ps[c]*invM;
    float var = pq[c]*invM - mu*mu;
    float rs = rsqrtf(var+BN_EPS);
    float v = G3[(size_t)r*DH + c];
    v = fmaxf((v-mu)*rs*gamma[c]+beta[c], 0.0f);
    sum += v*w4[c];
  }
  #pragma unroll
  for (int off=32; off>0; off>>=1) sum += __shfl_down(sum, off, 64);
  if (lane==0){
    float z = sum + b4[0];
    out[r] = 1.0f/(1.0f + expf(-z));
  }
}

extern "C" void kernel_launch(void* const* d_in, const int* in_sizes, int n_in,
                              void* d_out, int out_size, void* d_ws, size_t ws_size,
                              hipStream_t stream) {
  const float* x        = (const float*)d_in[0];
  const float* pg_emb   = (const float*)d_in[1];
  const float* neigh    = (const float*)d_in[2];
  const float* W_init   = (const float*)d_in[3];
  const float* b_init   = (const float*)d_in[4];
  const float* g1       = (const float*)d_in[5];
  const float* be1      = (const float*)d_in[6];
  const float* g2       = (const float*)d_in[7];
  const float* be2      = (const float*)d_in[8];
  const float* W_fc     = (const float*)d_in[9];
  const float* b_fc     = (const float*)d_in[10];
  const float* W_fc2    = (const float*)d_in[11];
  const float* b_fc2    = (const float*)d_in[12];
  const float* W_fc3    = (const float*)d_in[13];
  const float* b_fc3    = (const float*)d_in[14];
  const float* W_fc4    = (const float*)d_in[15];
  const float* b_fc4    = (const float*)d_in[16];
  const float* gb       = (const float*)d_in[17];
  const float* bb       = (const float*)d_in[18];
  const float* gb2      = (const float*)d_in[19];
  const float* bb2      = (const float*)d_in[20];
  const float* gb3      = (const float*)d_in[21];
  const float* bb3      = (const float*)d_in[22];
  const int*   esrc     = (const int*)d_in[23];
  const int*   edst     = (const int*)d_in[24];
  const int*   n2g      = (const int*)d_in[25];
  float* out = (float*)d_out;

  float* ws = (float*)d_ws;
  size_t off = 0;
  unsigned short* hb0 = (unsigned short*)(ws + off); off += (size_t)N_NODES*D/2; // bf16 raw h
  unsigned short* hb1 = (unsigned short*)(ws + off); off += (size_t)N_NODES*D/2; // bf16 raw layer1
  unsigned short* hb2 = (unsigned short*)(ws + off); off += (size_t)N_NODES*D/2; // bf16 raw layer2
  // ---- contiguous region zeroed by setup_kernel (ZCOUNT floats) ----
  float* zbase = ws + off;
  float* csum1 = ws + off; off += 512;
  float* csq1  = ws + off; off += 512;
  float* csum2 = ws + off; off += 512;
  float* csq2  = ws + off; off += 512;
  float* s1    = ws + off; off += 256;
  float* q1    = ws + off; off += 256;
  float* s2    = ws + off; off += 256;
  float* q2    = ws + off; off += 256;
  float* s3    = ws + off; off += 256;
  float* q3    = ws + off; off += 256;
  float* qemb  = ws + off; off += (size_t)B*D;        // 32768
  // ---- end zero region (36352 floats == ZCOUNT) ----
  float* G1   = ws + off; off += (size_t)NROW*DH;
  float* G2   = ws + off; off += (size_t)NROW*DH;
  float* G3   = ws + off; off += (size_t)NROW*DH;
  float* part = ws + off; off += (size_t)F1_NS*NROW*DH;
  int* degi     = (int*)(ws + off); off += N_NODES;
  int* rowstart = (int*)(ws + off); off += N_NODES + 1;
  int* cursor   = (int*)(ws + off); off += N_NODES;
  int* csr      = (int*)(ws + off); off += N_EDGES;
  int* gstart   = (int*)(ws + off); off += B + 1;
  (void)zbase;

  // ---- setup: zero scratch + graph bounds; then CSR build ----
  setup_kernel<<<SETUP_ZBLK+1, 256, 0, stream>>>(n2g, gstart, csum1, degi);
  deg_kernel<<<(N_EDGES+255)/256, 256, 0, stream>>>(edst, degi, N_EDGES);
  scan_kernel<<<1, 256, 0, stream>>>(degi, rowstart, cursor);
  fill_kernel<<<(N_EDGES+255)/256, 256, 0, stream>>>(esrc, edst, cursor, csr, N_EDGES);

  // ---- initial projection (bf16 out) ----
  init_mm_kernel<<<N_NODES/IM_ROWS, 256, 0, stream>>>(x, W_init, b_init, hb0);

  // ---- GIN layer 1: hb0 -> hb1 (raw), stats csum1/csq1 ----
  gin_gather_kernel<false><<<NWAVETOT/GWAVES, 256, 0, stream>>>(
      hb0, rowstart, csr, nullptr, nullptr, nullptr, nullptr, hb1, csum1, csq1);
  // ---- GIN layer 2: relu(BN1(hb1)) on the fly -> hb2 (raw), stats csum2/csq2 ----
  gin_gather_kernel<true><<<NWAVETOT/GWAVES, 256, 0, stream>>>(
      hb1, rowstart, csr, csum1, csq1, g1, be1, hb2, csum2, csq2);

  // ---- per-graph mean readout of relu(BN2(hb2)) ----
  readout_kernel<<<dim3(B, 8), 256, 0, stream>>>(hb2, csum2, csq2, g2, be2, gstart, qemb);

  // ---- MLP head (K-split partials + reduce w/ BN stats) ----
  fc1_partial_kernel<<<dim3(NROW/F1_ROWS, F1_NS), 256, 0, stream>>>(qemb, gstart, pg_emb, neigh, W_fc, part);
  reduce_stats_kernel<<<NROW/8, 256, 0, stream>>>(part, b_fc, G1, s1, q1, F1_NS);
  fc_mid_partial_kernel<<<dim3(NROW/FM_ROWS, FM_NS), 256, 0, stream>>>(G1, s1, q1, gb,  bb,  W_fc2, part);
  reduce_stats_kernel<<<NROW/8, 256, 0, stream>>>(part, b_fc2, G2, s2, q2, FM_NS);
  fc_mid_partial_kernel<<<dim3(NROW/FM_ROWS, FM_NS), 256, 0, stream>>>(G2, s2, q2, gb2, bb2, W_fc3, part);
  reduce_stats_kernel<<<NROW/8, 256, 0, stream>>>(part, b_fc3, G3, s3, q3, FM_NS);
  final_kernel<<<(NROW+3)/4, 256, 0, stream>>>(G3, s3, q3, gb3, bb3, W_fc4, b_fc4, out);
}